// Round 1
// baseline (1679.709 us; speedup 1.0000x reference)
//
#include <hip/hip_runtime.h>

#define NATOMS 2048
#define LDIM   16
#define CCH    64
#define NE     4
#define LOUTD  16
#define NK3    23
#define NK2    5
#define NK1    2
#define NM3    816   // #{i<=j<=k}
#define NM2    136   // #{i<=j}
#define NMTOT  968   // 816+136+16

#define APW    512   // atoms per workgroup (256 threads x 2)
#define MAXWG  4     // worst case all 2048 atoms one type

// ---------------- binning ----------------
__global__ void bin_kernel(const int* __restrict__ types, int* counts, int* bins) {
    int n = blockIdx.x * blockDim.x + threadIdx.x;
    if (n < NATOMS) {
        int t = types[n];
        int pos = atomicAdd(&counts[t], 1);
        bins[t * NATOMS + pos] = n;
    }
}

// ------------- prep: A[e][c][m][L] = sum_w Usym[m][L][w] * W[e][w][c] -------------
__global__ void prep_kernel(const float* __restrict__ U3, const float* __restrict__ U2,
                            const float* __restrict__ U1, const float* __restrict__ W3,
                            const float* __restrict__ W2, const float* __restrict__ W1,
                            float* __restrict__ A) {
    __shared__ float usym[LOUTD][NK3];
    int m = blockIdx.x;

    // decode m -> category + sorted indices (lexicographic rank, matches main loop order)
    int ci = 0, cj = 0, ck = 0, cat;
    if (m < NM3) {
        cat = 3;
        int cnt = 0;
        for (int i = 0; i < LDIM; i++)
            for (int j = i; j < LDIM; j++)
                for (int k = j; k < LDIM; k++) {
                    if (cnt == m) { ci = i; cj = j; ck = k; }
                    cnt++;
                }
    } else if (m < NM3 + NM2) {
        cat = 2;
        int mm = m - NM3, cnt = 0;
        for (int i = 0; i < LDIM; i++)
            for (int j = i; j < LDIM; j++) {
                if (cnt == mm) { ci = i; cj = j; }
                cnt++;
            }
    } else {
        cat = 1;
        ci = m - NM3 - NM2;
    }
    int Kc = (cat == 3) ? NK3 : (cat == 2) ? NK2 : NK1;

    int t = threadIdx.x;
    // phase 1: symmetrized U row for this monomial
    for (int idx = t; idx < LOUTD * Kc; idx += blockDim.x) {
        int L = idx / Kc, w = idx % Kc;
        float s = 0.f;
        if (cat == 3) {
            int pa[6], pb[6], pc[6];
            pa[0]=ci; pb[0]=cj; pc[0]=ck;  pa[1]=ci; pb[1]=ck; pc[1]=cj;
            pa[2]=cj; pb[2]=ci; pc[2]=ck;  pa[3]=cj; pb[3]=ck; pc[3]=ci;
            pa[4]=ck; pb[4]=ci; pc[4]=cj;  pa[5]=ck; pb[5]=cj; pc[5]=ci;
            int seen[6]; int ns = 0;
            for (int p = 0; p < 6; p++) {
                int code = (pa[p] << 8) | (pb[p] << 4) | pc[p];
                bool dup = false;
                for (int q = 0; q < ns; q++) if (seen[q] == code) dup = true;
                if (!dup) {
                    seen[ns++] = code;
                    s += U3[((((size_t)L * LDIM + pa[p]) * LDIM + pb[p]) * LDIM + pc[p]) * NK3 + w];
                }
            }
        } else if (cat == 2) {
            s = U2[(((size_t)L * LDIM + ci) * LDIM + cj) * NK2 + w];
            if (cj != ci) s += U2[(((size_t)L * LDIM + cj) * LDIM + ci) * NK2 + w];
        } else {
            s = U1[((size_t)L * LDIM + ci) * NK1 + w];
        }
        usym[L][w] = s;
    }
    __syncthreads();

    const float* W = (cat == 3) ? W3 : (cat == 2) ? W2 : W1;
    // phase 2: fold per-type weights; o = ((e*CCH + c)*LOUTD + L)
    for (int o = t; o < NE * CCH * LOUTD; o += blockDim.x) {
        int L = o & 15;
        int c = (o >> 4) & 63;
        int e = o >> 10;
        float s = 0.f;
        for (int w = 0; w < Kc; w++) s += usym[L][w] * W[(e * Kc + w) * CCH + c];
        A[((size_t)(e * CCH + c) * NMTOT + m) * LOUTD + L] = s;
    }
}

// ------------- main: out[n,L,c] = sum_m A[t,c,m,L] * mon_m -------------
__global__ __launch_bounds__(256) void main_kernel(
    const float* __restrict__ x, const int* __restrict__ counts,
    const int* __restrict__ bins, const float* __restrict__ A,
    float* __restrict__ out) {
    int e    = blockIdx.x / MAXWG;
    int slot = blockIdx.x % MAXWG;
    int c    = blockIdx.y;
    int cnt  = counts[e];
    int base = slot * APW;
    if (base >= cnt) return;

    __shared__ float xs[APW][LDIM + 1];  // pad 17: 2-way bank alias (free)
    int t = threadIdx.x;

    int n0 = -1, n1 = -1;
    {
        int a0 = base + t;
        if (a0 < cnt) {
            n0 = bins[e * NATOMS + a0];
            for (int i = 0; i < LDIM; i++) xs[t][i] = x[((size_t)n0 * LDIM + i) * CCH + c];
        } else {
            for (int i = 0; i < LDIM; i++) xs[t][i] = 0.f;
        }
        int a1 = base + 256 + t;
        if (a1 < cnt) {
            n1 = bins[e * NATOMS + a1];
            for (int i = 0; i < LDIM; i++) xs[t + 256][i] = x[((size_t)n1 * LDIM + i) * CCH + c];
        } else {
            for (int i = 0; i < LDIM; i++) xs[t + 256][i] = 0.f;
        }
    }
    __syncthreads();

    const float* __restrict__ Ar = A + (size_t)(e * CCH + c) * NMTOT * LOUTD;
    float acc0[LOUTD], acc1[LOUTD];
#pragma unroll
    for (int L = 0; L < LOUTD; L++) { acc0[L] = 0.f; acc1[L] = 0.f; }

    // order-3: lexicographic i<=j<=k, A rows sequential
    for (int i = 0; i < LDIM; i++) {
        float xi0 = xs[t][i], xi1 = xs[t + 256][i];
        for (int j = i; j < LDIM; j++) {
            float p0 = xi0 * xs[t][j], p1 = xi1 * xs[t + 256][j];
            for (int k = j; k < LDIM; k++) {
                float m0 = p0 * xs[t][k], m1 = p1 * xs[t + 256][k];
#pragma unroll
                for (int L = 0; L < LOUTD; L++) {
                    acc0[L] += Ar[L] * m0;
                    acc1[L] += Ar[L] * m1;
                }
                Ar += LOUTD;
            }
        }
    }
    // order-2
    for (int i = 0; i < LDIM; i++) {
        float xi0 = xs[t][i], xi1 = xs[t + 256][i];
        for (int j = i; j < LDIM; j++) {
            float m0 = xi0 * xs[t][j], m1 = xi1 * xs[t + 256][j];
#pragma unroll
            for (int L = 0; L < LOUTD; L++) {
                acc0[L] += Ar[L] * m0;
                acc1[L] += Ar[L] * m1;
            }
            Ar += LOUTD;
        }
    }
    // order-1
    for (int i = 0; i < LDIM; i++) {
        float m0 = xs[t][i], m1 = xs[t + 256][i];
#pragma unroll
        for (int L = 0; L < LOUTD; L++) {
            acc0[L] += Ar[L] * m0;
            acc1[L] += Ar[L] * m1;
        }
        Ar += LOUTD;
    }

    if (n0 >= 0)
        for (int L = 0; L < LOUTD; L++) out[((size_t)n0 * LOUTD + L) * CCH + c] = acc0[L];
    if (n1 >= 0)
        for (int L = 0; L < LOUTD; L++) out[((size_t)n1 * LOUTD + L) * CCH + c] = acc1[L];
}

extern "C" void kernel_launch(void* const* d_in, const int* in_sizes, int n_in,
                              void* d_out, int out_size, void* d_ws, size_t ws_size,
                              hipStream_t stream) {
    const float* x   = (const float*)d_in[0];
    const int* types = (const int*)d_in[1];
    const float* U3  = (const float*)d_in[2];
    const float* U2  = (const float*)d_in[3];
    const float* U1  = (const float*)d_in[4];
    const float* W3  = (const float*)d_in[5];
    const float* W2  = (const float*)d_in[6];
    const float* W1  = (const float*)d_in[7];
    float* out = (float*)d_out;

    char* ws   = (char*)d_ws;
    int* counts = (int*)ws;                    // 16 B
    int* bins   = (int*)(ws + 256);            // 32 KB
    float* A    = (float*)(ws + 65536);        // ~15.9 MB

    hipMemsetAsync(counts, 0, NE * sizeof(int), stream);
    bin_kernel<<<(NATOMS + 255) / 256, 256, 0, stream>>>(types, counts, bins);
    prep_kernel<<<NMTOT, 256, 0, stream>>>(U3, U2, U1, W3, W2, W1, A);
    main_kernel<<<dim3(NE * MAXWG, CCH), 256, 0, stream>>>(x, counts, bins, A, out);
}

// Round 2
// 319.305 us; speedup vs baseline: 5.2605x; 5.2605x over previous
//
#include <hip/hip_runtime.h>
#include <hip/hip_fp16.h>

#define NATOMS 2048
#define CCH    64
#define NE     4

#define NP    136     // #{i<=j} pairs over 16
#define K3DIM 2176    // 136*16 inflated order-3 K
#define M2B   2176
#define M1B   2312
#define KTOT  2328
#define NSTEP 73      // ceil(2336/32)

typedef _Float16 f16x8 __attribute__((ext_vector_type(8)));
typedef float f32x4 __attribute__((ext_vector_type(4)));

__host__ __device__ constexpr int pair_i(int p){ int i=0, rem=p; while (rem >= 16-i){ rem -= 16-i; ++i; } return i; }
__host__ __device__ constexpr int pair_j(int p){ int i=0, rem=p; while (rem >= 16-i){ rem -= 16-i; ++i; } return i+rem; }

template<int N> struct IC { static constexpr int value = N; };
template<int S, int E, typename F> __device__ __forceinline__ void sfor(F&& f){
  if constexpr (S < E){ f(IC<S>{}); sfor<S+1,E>(f); }
}

// monomial value for tail region (m >= M2B), compile-time M
template<int M> __device__ __forceinline__ float monval(const float (&xf)[16]){
  if constexpr (M >= KTOT) { (void)xf; return 0.f; }
  else if constexpr (M >= M1B) return xf[M - M1B];
  else {
    constexpr int p  = M - M2B;
    constexpr int i0 = pair_i(p), j0 = pair_j(p);
    return xf[i0] * xf[j0];
  }
}

template<int S, int G> __device__ __forceinline__ f16x8 tailfrag(const float (&xf)[16]){
  union { __half2 h[4]; f16x8 v; } u;
#define TE(E2) { float lo = monval<32*S+8*G+2*E2>(xf); float hi = monval<32*S+8*G+2*E2+1>(xf); \
                 u.h[E2] = __halves2half2(__float2half(lo), __float2half(hi)); }
  TE(0) TE(1) TE(2) TE(3)
#undef TE
  return u.v;
}

// ---------------- binning ----------------
__global__ void bin_kernel(const int* __restrict__ types, int* counts, int* bins){
  int n = blockIdx.x * blockDim.x + threadIdx.x;
  if (n < NATOMS){
    int t = types[n];
    int pos = atomicAdd(&counts[t], 1);
    bins[t * NATOMS + pos] = n;
  }
}

// ---------------- prep: Bbuf fragments ----------------
// Bbuf dword index: (((e*CN + cl)*NSTEP + s)*64 + l)*4 + r
// holds half2 { A(e,c,m0,L), A(e,c,m0+1,L) }, m0 = 32s+8*(l>>4)+2r, L = l&15
__global__ __launch_bounds__(256) void prep_kernel(
    const float* __restrict__ U3, const float* __restrict__ U2,
    const float* __restrict__ U1, const float* __restrict__ W3,
    const float* __restrict__ W2, const float* __restrict__ W1,
    unsigned int* __restrict__ Bbuf, int CB, int CN){
  int s = blockIdx.x, e = blockIdx.y, cz = blockIdx.z;
  int tid = threadIdx.x;
  int l = tid >> 2, r = tid & 3;
  int g = l >> 4, L = l & 15;
  int m0 = 32*s + 8*g + 2*r;

  __shared__ float WL[30][16];
  {
    int cbase = CB + cz*16;
    for (int t = tid; t < 30*16; t += 256){
      int row = t >> 4, cc = t & 15;
      float v;
      if (row < 23)      v = W3[((size_t)e*23 + row)*CCH + cbase + cc];
      else if (row < 28) v = W2[((size_t)e*5 + (row-23))*CCH + cbase + cc];
      else               v = W1[((size_t)e*2 + (row-28))*CCH + cbase + cc];
      WL[row][cc] = v;
    }
  }
  __syncthreads();

  float us0[23], us1[23];
#pragma unroll
  for (int w = 0; w < 23; ++w){ us0[w] = 0.f; us1[w] = 0.f; }

  auto gather = [&](int m, float (&us)[23]) -> int {
    if (m >= KTOT) return 0;
    if (m >= M1B){
      int i = m - M1B;
#pragma unroll
      for (int w = 0; w < 2; ++w) us[w] = U1[((size_t)L*16 + i)*2 + w];
      return 1;
    }
    if (m >= M2B){
      int p = m - M2B;
      int i = 0, rem = p; while (rem >= 16-i){ rem -= 16-i; ++i; }
      int j = i + rem;
#pragma unroll
      for (int w = 0; w < 5; ++w){
        float v = U2[(((size_t)L*16 + i)*16 + j)*5 + w];
        if (i < j) v += U2[(((size_t)L*16 + j)*16 + i)*5 + w];
        us[w] = v;
      }
      return 2;
    }
    int p = m >> 4, k = m & 15;
    int i = 0, rem = p; while (rem >= 16-i){ rem -= 16-i; ++i; }
    int j = i + rem;
#pragma unroll
    for (int w = 0; w < 23; ++w){
      float v = U3[((((size_t)L*16 + i)*16 + j)*16 + k)*23 + w];
      if (i < j) v += U3[((((size_t)L*16 + j)*16 + i)*16 + k)*23 + w];
      us[w] = v;
    }
    return 3;
  };

  int cat = gather(m0, us0);
  (void)gather(m0 + 1, us1);

  for (int cc = 0; cc < 16; ++cc){
    float a0 = 0.f, a1 = 0.f;
    if (cat == 3){
#pragma unroll
      for (int w = 0; w < 23; ++w){ float wv = WL[w][cc]; a0 += us0[w]*wv; a1 += us1[w]*wv; }
    } else if (cat == 2){
#pragma unroll
      for (int w = 0; w < 5; ++w){ float wv = WL[23+w][cc]; a0 += us0[w]*wv; a1 += us1[w]*wv; }
    } else if (cat == 1){
#pragma unroll
      for (int w = 0; w < 2; ++w){ float wv = WL[28+w][cc]; a0 += us0[w]*wv; a1 += us1[w]*wv; }
    }
    union { __half2 h; unsigned int u; } hu;
    hu.h = __halves2half2(__float2half(a0), __float2half(a1));
    int cl = cz*16 + cc;
    Bbuf[(((size_t)(e*CN + cl)*NSTEP + s)*64 + l)*4 + r] = hu.u;
  }
}

// ---------------- main: per-wave 32-atom x K GEMM via MFMA ----------------
__global__ __launch_bounds__(256) void main_kernel(
    const float* __restrict__ x, const int* __restrict__ counts,
    const int* __restrict__ bins, const uint4* __restrict__ Bbuf,
    float* __restrict__ out, int CB, int CN){
  int lane = threadIdx.x & 63;
  int wid  = threadIdx.x >> 6;
  int W = blockIdx.x * 4 + wid;
  int e = W >> 6, slot = W & 63;
  int cnt = counts[e];
  if (slot * 32 >= cnt) return;
  int cl = blockIdx.y;
  int c  = CB + cl;

  int aL = slot*32 + (lane & 15);
  int aH = aL + 16;
  int nL = (aL < cnt) ? bins[e*NATOMS + aL] : -1;
  int nH = (aH < cnt) ? bins[e*NATOMS + aH] : -1;

  float xL[16], xH[16];
#pragma unroll
  for (int i = 0; i < 16; ++i){
    xL[i] = (nL >= 0) ? x[((size_t)nL*16 + i)*CCH + c] : 0.f;
    xH[i] = (nH >= 0) ? x[((size_t)nH*16 + i)*CCH + c] : 0.f;
  }

  bool hi_half = (lane & 16) != 0;
  __half2 xselL[4], xselH[4];
#pragma unroll
  for (int q = 0; q < 4; ++q){
    int b0 = (hi_half ? 8 : 0) + 2*q;
    xselL[q] = __halves2half2(__float2half(xL[b0]), __float2half(xL[b0+1]));
    xselH[q] = __halves2half2(__float2half(xH[b0]), __float2half(xH[b0+1]));
  }
  bool gsel = (lane & 32) != 0;

  const uint4* Bp = Bbuf + ((size_t)(e*CN + cl))*NSTEP*64 + lane;

  f32x4 accL = {0.f,0.f,0.f,0.f}, accH = {0.f,0.f,0.f,0.f};
  uint4 b0v = Bp[0];
  uint4 b1v = Bp[64];

  sfor<0, NSTEP>([&](auto sc){
    constexpr int s = decltype(sc)::value;
    uint4 bn;
    if constexpr (s + 2 < NSTEP) bn = Bp[(size_t)(s+2)*64];
    else bn = make_uint4(0u,0u,0u,0u);

    f16x8 afL, afH;
    if constexpr (32*(s+1) <= K3DIM){           // pure order-3 step
      constexpr int p0 = 2*s, p1 = 2*s + 1;
      constexpr int iA = pair_i(p0), jA = pair_j(p0);
      constexpr int iB = pair_i(p1), jB = pair_j(p1);
      float pAL = xL[iA]*xL[jA], pBL = xL[iB]*xL[jB];
      float pAH = xH[iA]*xH[jA], pBH = xH[iB]*xH[jB];
      __half2 pvL = __float2half2_rn(gsel ? pBL : pAL);
      __half2 pvH = __float2half2_rn(gsel ? pBH : pAH);
      union { __half2 h[4]; f16x8 v; } uL, uH;
#pragma unroll
      for (int q = 0; q < 4; ++q){
        uL.h[q] = __hmul2(pvL, xselL[q]);
        uH.h[q] = __hmul2(pvH, xselH[q]);
      }
      afL = uL.v; afH = uH.v;
    } else {                                     // tail: order-2/1/pad
      int g = (lane >> 4) & 3;
      if      (g == 0){ afL = tailfrag<s,0>(xL); afH = tailfrag<s,0>(xH); }
      else if (g == 1){ afL = tailfrag<s,1>(xL); afH = tailfrag<s,1>(xH); }
      else if (g == 2){ afL = tailfrag<s,2>(xL); afH = tailfrag<s,2>(xH); }
      else            { afL = tailfrag<s,3>(xL); afH = tailfrag<s,3>(xH); }
    }
    union { uint4 u; f16x8 v; } bc; bc.u = b0v;
    accL = __builtin_amdgcn_mfma_f32_16x16x32_f16(afL, bc.v, accL, 0, 0, 0);
    accH = __builtin_amdgcn_mfma_f32_16x16x32_f16(afH, bc.v, accH, 0, 0, 0);
    b0v = b1v; b1v = bn;
  });

  int gp = lane >> 4, L = lane & 15;
#pragma unroll
  for (int r = 0; r < 4; ++r){
    int pl = slot*32 + 4*gp + r;
    if (pl < cnt){ int n = bins[e*NATOMS + pl]; out[((size_t)n*16 + L)*CCH + c] = accL[r]; }
    int ph = pl + 16;
    if (ph < cnt){ int n = bins[e*NATOMS + ph]; out[((size_t)n*16 + L)*CCH + c] = accH[r]; }
  }
}

extern "C" void kernel_launch(void* const* d_in, const int* in_sizes, int n_in,
                              void* d_out, int out_size, void* d_ws, size_t ws_size,
                              hipStream_t stream){
  const float* x   = (const float*)d_in[0];
  const int* types = (const int*)d_in[1];
  const float* U3  = (const float*)d_in[2];
  const float* U2  = (const float*)d_in[3];
  const float* U1  = (const float*)d_in[4];
  const float* W3  = (const float*)d_in[5];
  const float* W2  = (const float*)d_in[6];
  const float* W1  = (const float*)d_in[7];
  float* out = (float*)d_out;

  char* ws = (char*)d_ws;
  int* counts = (int*)ws;                       // 256 B
  int* bins   = (int*)(ws + 256);               // 32 KB
  unsigned int* Bbuf = (unsigned int*)(ws + 33280);

  size_t needBig = 33280 + (size_t)NE * 64 * NSTEP * 64 * 16;  // ~19.2 MB
  bool big = ws_size >= needBig;

  hipMemsetAsync(counts, 0, NE * sizeof(int), stream);
  bin_kernel<<<(NATOMS + 255) / 256, 256, 0, stream>>>(types, counts, bins);

  if (big){
    prep_kernel<<<dim3(NSTEP, NE, 4), 256, 0, stream>>>(U3,U2,U1,W3,W2,W1,Bbuf,0,64);
    main_kernel<<<dim3(64, 64), 256, 0, stream>>>(x, counts, bins, (const uint4*)Bbuf, out, 0, 64);
  } else {
    prep_kernel<<<dim3(NSTEP, NE, 2), 256, 0, stream>>>(U3,U2,U1,W3,W2,W1,Bbuf,0,32);
    main_kernel<<<dim3(64, 32), 256, 0, stream>>>(x, counts, bins, (const uint4*)Bbuf, out, 0, 32);
    prep_kernel<<<dim3(NSTEP, NE, 2), 256, 0, stream>>>(U3,U2,U1,W3,W2,W1,Bbuf,32,32);
    main_kernel<<<dim3(64, 32), 256, 0, stream>>>(x, counts, bins, (const uint4*)Bbuf, out, 32, 32);
  }
}

// Round 3
// 247.573 us; speedup vs baseline: 6.7847x; 1.2897x over previous
//
#include <hip/hip_runtime.h>
#include <hip/hip_fp16.h>

#define NATOMS 2048
#define CCH    64
#define NE     4

#define NP    136     // #{i<=j} pairs over 16
#define K3DIM 2176    // 136*16 inflated order-3 K
#define M2B   2176
#define M1B   2312
#define KTOT  2328
#define KPAD  2336
#define NSTEP 73      // KPAD/32

typedef _Float16 f16x8 __attribute__((ext_vector_type(8)));
typedef float f32x4 __attribute__((ext_vector_type(4)));

__host__ __device__ constexpr int pair_i(int p){ int i=0, rem=p; while (rem >= 16-i){ rem -= 16-i; ++i; } return i; }
__host__ __device__ constexpr int pair_j(int p){ int i=0, rem=p; while (rem >= 16-i){ rem -= 16-i; ++i; } return i+rem; }

template<int N> struct IC { static constexpr int value = N; };
template<int S, int E, typename F> __device__ __forceinline__ void sfor(F&& f){
  if constexpr (S < E){ f(IC<S>{}); sfor<S+1,E>(f); }
}

// monomial value for tail region (m >= M2B), compile-time M
template<int M> __device__ __forceinline__ float monval(const float (&xf)[16]){
  if constexpr (M >= KTOT) { (void)xf; return 0.f; }
  else if constexpr (M >= M1B) return xf[M - M1B];
  else {
    constexpr int p  = M - M2B;
    constexpr int i0 = pair_i(p), j0 = pair_j(p);
    return xf[i0] * xf[j0];
  }
}

template<int S, int G> __device__ __forceinline__ f16x8 tailfrag(const float (&xf)[16]){
  union { __half2 h[4]; f16x8 v; } u;
#define TE(E2) { float lo = monval<32*S+8*G+2*E2>(xf); float hi = monval<32*S+8*G+2*E2+1>(xf); \
                 u.h[E2] = __halves2half2(__float2half(lo), __float2half(hi)); }
  TE(0) TE(1) TE(2) TE(3)
#undef TE
  return u.v;
}

// ---------------- binning ----------------
__global__ void bin_kernel(const int* __restrict__ types, int* counts, int* bins){
  int n = blockIdx.x * blockDim.x + threadIdx.x;
  if (n < NATOMS){
    int t = types[n];
    int pos = atomicAdd(&counts[t], 1);
    bins[t * NATOMS + pos] = n;
  }
}

// ---------------- usym: symmetrized CG rows, computed ONCE ----------------
// Us[m][L][24] f32; w-local per category, zero-padded.
__global__ __launch_bounds__(256) void usym_kernel(
    const float* __restrict__ U3, const float* __restrict__ U2,
    const float* __restrict__ U1, float* __restrict__ Us){
  int gid = blockIdx.x * 256 + threadIdx.x;
  if (gid >= KPAD * 16) return;
  int m = gid >> 4, L = gid & 15;
  float us[24];
#pragma unroll
  for (int w = 0; w < 24; ++w) us[w] = 0.f;

  if (m < M2B){
    int p = m >> 4, k = m & 15;
    int i = 0, rem = p; while (rem >= 16 - i){ rem -= 16 - i; ++i; }
    int j = i + rem;
    const float* r0 = &U3[((((size_t)L*16 + i)*16 + j)*16 + k)*23];
    if (i < j){
      const float* r1 = &U3[((((size_t)L*16 + j)*16 + i)*16 + k)*23];
#pragma unroll
      for (int w = 0; w < 23; ++w) us[w] = r0[w] + r1[w];
    } else {
#pragma unroll
      for (int w = 0; w < 23; ++w) us[w] = r0[w];
    }
  } else if (m < M1B){
    int p = m - M2B;
    int i = 0, rem = p; while (rem >= 16 - i){ rem -= 16 - i; ++i; }
    int j = i + rem;
#pragma unroll
    for (int w = 0; w < 5; ++w){
      float v = U2[(((size_t)L*16 + i)*16 + j)*5 + w];
      if (i < j) v += U2[(((size_t)L*16 + j)*16 + i)*5 + w];
      us[w] = v;
    }
  } else if (m < KTOT){
    int i = m - M1B;
    us[0] = U1[((size_t)L*16 + i)*2 + 0];
    us[1] = U1[((size_t)L*16 + i)*2 + 1];
  }

  float4* dst = (float4*)(Us + ((size_t)m*16 + L)*24);
#pragma unroll
  for (int q = 0; q < 6; ++q) dst[q] = ((const float4*)us)[q];
}

// ---------------- fold: Bbuf[e][c][s][l][r] = half2{A(m0),A(m0+1)} ----------------
__global__ __launch_bounds__(256) void fold_kernel(
    const float* __restrict__ Us, const float* __restrict__ W3,
    const float* __restrict__ W2, const float* __restrict__ W1,
    unsigned int* __restrict__ Bbuf, int CB, int CN){
  int s = blockIdx.x, e = blockIdx.y;
  int tid = threadIdx.x;
  int l = tid >> 2, r = tid & 3, g = l >> 4, L = l & 15;
  int m0 = 32*s + 8*g + 2*r;

  __shared__ float WL[30][CCH];
  for (int t = tid; t < 30*CCH; t += 256){
    int row = t >> 6, cc = t & 63;
    float v;
    if (row < 23)      v = W3[((size_t)e*23 + row)*CCH + cc];
    else if (row < 28) v = W2[((size_t)e*5 + (row-23))*CCH + cc];
    else               v = W1[((size_t)e*2 + (row-28))*CCH + cc];
    WL[row][cc] = v;
  }

  float u0[24], u1[24];
  const float4* s0 = (const float4*)(Us + ((size_t)m0*16 + L)*24);
  const float4* s1 = (const float4*)(Us + ((size_t)(m0+1)*16 + L)*24);
#pragma unroll
  for (int q = 0; q < 6; ++q){ ((float4*)u0)[q] = s0[q]; ((float4*)u1)[q] = s1[q]; }

  int wbase, K;
  if (m0 < M2B){ wbase = 0; K = 23; }
  else if (m0 < M1B){ wbase = 23; K = 5; }
  else { wbase = 28; K = 2; }
  __syncthreads();

  for (int cc = 0; cc < CN; ++cc){
    int c = CB + cc;
    float a0 = 0.f, a1 = 0.f;
    for (int w = 0; w < K; ++w){
      float wv = WL[wbase + w][c];
      a0 += u0[w]*wv; a1 += u1[w]*wv;
    }
    union { __half2 h; unsigned int u; } hu;
    hu.h = __halves2half2(__float2half(a0), __float2half(a1));
    Bbuf[(((size_t)(e*CN + cc)*NSTEP + s)*64 + l)*4 + r] = hu.u;
  }
}

// ---------------- legacy prep (fallback when ws too small) ----------------
__global__ __launch_bounds__(256) void prep_kernel(
    const float* __restrict__ U3, const float* __restrict__ U2,
    const float* __restrict__ U1, const float* __restrict__ W3,
    const float* __restrict__ W2, const float* __restrict__ W1,
    unsigned int* __restrict__ Bbuf, int CB, int CN){
  int s = blockIdx.x, e = blockIdx.y, cz = blockIdx.z;
  int tid = threadIdx.x;
  int l = tid >> 2, r = tid & 3;
  int g = l >> 4, L = l & 15;
  int m0 = 32*s + 8*g + 2*r;

  __shared__ float WL[30][16];
  {
    int cbase = CB + cz*16;
    for (int t = tid; t < 30*16; t += 256){
      int row = t >> 4, cc = t & 15;
      float v;
      if (row < 23)      v = W3[((size_t)e*23 + row)*CCH + cbase + cc];
      else if (row < 28) v = W2[((size_t)e*5 + (row-23))*CCH + cbase + cc];
      else               v = W1[((size_t)e*2 + (row-28))*CCH + cbase + cc];
      WL[row][cc] = v;
    }
  }
  __syncthreads();

  float us0[23], us1[23];
#pragma unroll
  for (int w = 0; w < 23; ++w){ us0[w] = 0.f; us1[w] = 0.f; }

  auto gather = [&](int m, float (&us)[23]) -> int {
    if (m >= KTOT) return 0;
    if (m >= M1B){
      int i = m - M1B;
#pragma unroll
      for (int w = 0; w < 2; ++w) us[w] = U1[((size_t)L*16 + i)*2 + w];
      return 1;
    }
    if (m >= M2B){
      int p = m - M2B;
      int i = 0, rem = p; while (rem >= 16-i){ rem -= 16-i; ++i; }
      int j = i + rem;
#pragma unroll
      for (int w = 0; w < 5; ++w){
        float v = U2[(((size_t)L*16 + i)*16 + j)*5 + w];
        if (i < j) v += U2[(((size_t)L*16 + j)*16 + i)*5 + w];
        us[w] = v;
      }
      return 2;
    }
    int p = m >> 4, k = m & 15;
    int i = 0, rem = p; while (rem >= 16-i){ rem -= 16-i; ++i; }
    int j = i + rem;
#pragma unroll
    for (int w = 0; w < 23; ++w){
      float v = U3[((((size_t)L*16 + i)*16 + j)*16 + k)*23 + w];
      if (i < j) v += U3[((((size_t)L*16 + j)*16 + i)*16 + k)*23 + w];
      us[w] = v;
    }
    return 3;
  };

  int cat = gather(m0, us0);
  (void)gather(m0 + 1, us1);

  for (int cc = 0; cc < 16; ++cc){
    float a0 = 0.f, a1 = 0.f;
    if (cat == 3){
#pragma unroll
      for (int w = 0; w < 23; ++w){ float wv = WL[w][cc]; a0 += us0[w]*wv; a1 += us1[w]*wv; }
    } else if (cat == 2){
#pragma unroll
      for (int w = 0; w < 5; ++w){ float wv = WL[23+w][cc]; a0 += us0[w]*wv; a1 += us1[w]*wv; }
    } else if (cat == 1){
#pragma unroll
      for (int w = 0; w < 2; ++w){ float wv = WL[28+w][cc]; a0 += us0[w]*wv; a1 += us1[w]*wv; }
    }
    union { __half2 h; unsigned int u; } hu;
    hu.h = __halves2half2(__float2half(a0), __float2half(a1));
    int cl = cz*16 + cc;
    Bbuf[(((size_t)(e*CN + cl)*NSTEP + s)*64 + l)*4 + r] = hu.u;
  }
}

// ---------------- main: per-wave 32-atom x K GEMM via MFMA ----------------
// 1-D grid = NE*CN*16 blocks; XCD swizzle pins each (e,c) panel to one XCD.
__global__ __launch_bounds__(256) void main_kernel(
    const float* __restrict__ x, const int* __restrict__ counts,
    const int* __restrict__ bins, const uint4* __restrict__ Bbuf,
    float* __restrict__ out, int CB, int CN){
  int lane = threadIdx.x & 63;
  int wid  = threadIdx.x >> 6;
  int d = blockIdx.x;
  int xcd = d & 7, q = d >> 3;
  int pg = q >> 4, sb = q & 15;
  int p = xcd + 8*pg;                 // panel id, all 16 blocks of a panel on one XCD
  int e = p / CN, cl = p % CN;
  int slot = sb*4 + wid;              // 0..63
  int cnt = counts[e];
  if (slot * 32 >= cnt) return;
  int c = CB + cl;

  int aL = slot*32 + (lane & 15);
  int aH = aL + 16;
  int nL = (aL < cnt) ? bins[e*NATOMS + aL] : -1;
  int nH = (aH < cnt) ? bins[e*NATOMS + aH] : -1;

  float xL[16], xH[16];
#pragma unroll
  for (int i = 0; i < 16; ++i){
    xL[i] = (nL >= 0) ? x[((size_t)nL*16 + i)*CCH + c] : 0.f;
    xH[i] = (nH >= 0) ? x[((size_t)nH*16 + i)*CCH + c] : 0.f;
  }

  bool hi_half = (lane & 16) != 0;
  __half2 xselL[4], xselH[4];
#pragma unroll
  for (int q2 = 0; q2 < 4; ++q2){
    int b0 = (hi_half ? 8 : 0) + 2*q2;
    xselL[q2] = __halves2half2(__float2half(xL[b0]), __float2half(xL[b0+1]));
    xselH[q2] = __halves2half2(__float2half(xH[b0]), __float2half(xH[b0+1]));
  }
  bool gsel = (lane & 32) != 0;

  const uint4* Bp = Bbuf + ((size_t)(e*CN + cl))*NSTEP*64 + lane;

  f32x4 accL = {0.f,0.f,0.f,0.f}, accH = {0.f,0.f,0.f,0.f};
  uint4 buf0 = Bp[0];
  uint4 buf1 = Bp[64];
  uint4 buf2 = Bp[128];
  uint4 buf3 = Bp[192];

  sfor<0, NSTEP>([&](auto sc){
    constexpr int s = decltype(sc)::value;
    constexpr int slt = s & 3;
    uint4 cur;
    if constexpr (slt == 0) cur = buf0;
    else if constexpr (slt == 1) cur = buf1;
    else if constexpr (slt == 2) cur = buf2;
    else cur = buf3;
    if constexpr (s + 4 < NSTEP){
      if constexpr (slt == 0) buf0 = Bp[(size_t)(s+4)*64];
      else if constexpr (slt == 1) buf1 = Bp[(size_t)(s+4)*64];
      else if constexpr (slt == 2) buf2 = Bp[(size_t)(s+4)*64];
      else buf3 = Bp[(size_t)(s+4)*64];
    }

    f16x8 afL, afH;
    if constexpr (32*(s+1) <= K3DIM){           // pure order-3 step
      constexpr int p0 = 2*s, p1 = 2*s + 1;
      constexpr int iA = pair_i(p0), jA = pair_j(p0);
      constexpr int iB = pair_i(p1), jB = pair_j(p1);
      float pAL = xL[iA]*xL[jA], pBL = xL[iB]*xL[jB];
      float pAH = xH[iA]*xH[jA], pBH = xH[iB]*xH[jB];
      __half2 pvL = __float2half2_rn(gsel ? pBL : pAL);
      __half2 pvH = __float2half2_rn(gsel ? pBH : pAH);
      union { __half2 h[4]; f16x8 v; } uL, uH;
#pragma unroll
      for (int q2 = 0; q2 < 4; ++q2){
        uL.h[q2] = __hmul2(pvL, xselL[q2]);
        uH.h[q2] = __hmul2(pvH, xselH[q2]);
      }
      afL = uL.v; afH = uH.v;
    } else {                                     // tail: order-2/1/pad
      int g = (lane >> 4) & 3;
      if      (g == 0){ afL = tailfrag<s,0>(xL); afH = tailfrag<s,0>(xH); }
      else if (g == 1){ afL = tailfrag<s,1>(xL); afH = tailfrag<s,1>(xH); }
      else if (g == 2){ afL = tailfrag<s,2>(xL); afH = tailfrag<s,2>(xH); }
      else            { afL = tailfrag<s,3>(xL); afH = tailfrag<s,3>(xH); }
    }
    union { uint4 u; f16x8 v; } bc; bc.u = cur;
    accL = __builtin_amdgcn_mfma_f32_16x16x32_f16(afL, bc.v, accL, 0, 0, 0);
    accH = __builtin_amdgcn_mfma_f32_16x16x32_f16(afH, bc.v, accH, 0, 0, 0);
  });

  int gp = lane >> 4, L = lane & 15;
#pragma unroll
  for (int r = 0; r < 4; ++r){
    int pl = slot*32 + 4*gp + r;
    if (pl < cnt){ int n = bins[e*NATOMS + pl]; out[((size_t)n*16 + L)*CCH + c] = accL[r]; }
    int ph = pl + 16;
    if (ph < cnt){ int n = bins[e*NATOMS + ph]; out[((size_t)n*16 + L)*CCH + c] = accH[r]; }
  }
}

extern "C" void kernel_launch(void* const* d_in, const int* in_sizes, int n_in,
                              void* d_out, int out_size, void* d_ws, size_t ws_size,
                              hipStream_t stream){
  const float* x   = (const float*)d_in[0];
  const int* types = (const int*)d_in[1];
  const float* U3  = (const float*)d_in[2];
  const float* U2  = (const float*)d_in[3];
  const float* U1  = (const float*)d_in[4];
  const float* W3  = (const float*)d_in[5];
  const float* W2  = (const float*)d_in[6];
  const float* W1  = (const float*)d_in[7];
  float* out = (float*)d_out;

  char* ws = (char*)d_ws;
  int* counts = (int*)ws;                        // 256 B
  int* bins   = (int*)(ws + 256);                // 32 KB -> offset 33280 aligned
  const size_t usOff   = 33280;
  const size_t usBytes = (size_t)KPAD * 16 * 24 * 4;          // 3,588,096
  const size_t bbOff   = (usOff + usBytes + 511) & ~(size_t)511;
  const size_t bbBytes = (size_t)NE * 64 * NSTEP * 64 * 16;   // 19,136,512

  hipMemsetAsync(counts, 0, NE * sizeof(int), stream);
  bin_kernel<<<(NATOMS + 255) / 256, 256, 0, stream>>>(types, counts, bins);

  if (ws_size >= bbOff + bbBytes){
    // fast path: usym once + coalesced fold
    float* Us = (float*)(ws + usOff);
    unsigned int* Bbuf = (unsigned int*)(ws + bbOff);
    usym_kernel<<<(KPAD*16 + 255)/256, 256, 0, stream>>>(U3, U2, U1, Us);
    fold_kernel<<<dim3(NSTEP, NE), 256, 0, stream>>>(Us, W3, W2, W1, Bbuf, 0, 64);
    main_kernel<<<dim3(NE*64*16), 256, 0, stream>>>(x, counts, bins, (const uint4*)Bbuf, out, 0, 64);
  } else if (ws_size >= 33280 + bbBytes){
    unsigned int* Bbuf = (unsigned int*)(ws + 33280);
    prep_kernel<<<dim3(NSTEP, NE, 4), 256, 0, stream>>>(U3,U2,U1,W3,W2,W1,Bbuf,0,64);
    main_kernel<<<dim3(NE*64*16), 256, 0, stream>>>(x, counts, bins, (const uint4*)Bbuf, out, 0, 64);
  } else {
    unsigned int* Bbuf = (unsigned int*)(ws + 33280);
    prep_kernel<<<dim3(NSTEP, NE, 2), 256, 0, stream>>>(U3,U2,U1,W3,W2,W1,Bbuf,0,32);
    main_kernel<<<dim3(NE*32*16), 256, 0, stream>>>(x, counts, bins, (const uint4*)Bbuf, out, 0, 32);
    prep_kernel<<<dim3(NSTEP, NE, 2), 256, 0, stream>>>(U3,U2,U1,W3,W2,W1,Bbuf,32,32);
    main_kernel<<<dim3(NE*32*16), 256, 0, stream>>>(x, counts, bins, (const uint4*)Bbuf, out, 32, 32);
  }
}

// Round 4
// 121.916 us; speedup vs baseline: 13.7776x; 2.0307x over previous
//
#include <hip/hip_runtime.h>
#include <hip/hip_fp16.h>

#define NATOMS 2048
#define CCH    64
#define NE     4

#define NP    136     // #{i<=j} pairs over 16
#define K3DIM 2176    // 136*16 inflated order-3 K
#define M2B   2176
#define M1B   2312
#define KTOT  2328
#define KPAD  2336
#define NSTEP 73      // KPAD/32

typedef _Float16 f16x8 __attribute__((ext_vector_type(8)));
typedef float f32x4 __attribute__((ext_vector_type(4)));

__host__ __device__ constexpr int pair_i(int p){ int i=0, rem=p; while (rem >= 16-i){ rem -= 16-i; ++i; } return i; }
__host__ __device__ constexpr int pair_j(int p){ int i=0, rem=p; while (rem >= 16-i){ rem -= 16-i; ++i; } return i+rem; }

template<int N> struct IC { static constexpr int value = N; };
template<int S, int E, typename F> __device__ __forceinline__ void sfor(F&& f){
  if constexpr (S < E){ f(IC<S>{}); sfor<S+1,E>(f); }
}

// monomial value for tail region (m >= M2B), compile-time M
template<int M> __device__ __forceinline__ float monval(const float (&xf)[16]){
  if constexpr (M >= KTOT) { (void)xf; return 0.f; }
  else if constexpr (M >= M1B) return xf[M - M1B];
  else {
    constexpr int p  = M - M2B;
    constexpr int i0 = pair_i(p), j0 = pair_j(p);
    return xf[i0] * xf[j0];
  }
}

template<int S, int G> __device__ __forceinline__ f16x8 tailfrag(const float (&xf)[16]){
  union { __half2 h[4]; f16x8 v; } u;
#define TE(E2) { float lo = monval<32*S+8*G+2*E2>(xf); float hi = monval<32*S+8*G+2*E2+1>(xf); \
                 u.h[E2] = __halves2half2(__float2half(lo), __float2half(hi)); }
  TE(0) TE(1) TE(2) TE(3)
#undef TE
  return u.v;
}

// ---------------- binning ----------------
__global__ void bin_kernel(const int* __restrict__ types, int* counts, int* bins){
  int n = blockIdx.x * blockDim.x + threadIdx.x;
  if (n < NATOMS){
    int t = types[n];
    int pos = atomicAdd(&counts[t], 1);
    bins[t * NATOMS + pos] = n;
  }
}

// ---------------- usym: symmetrized CG rows, computed ONCE ----------------
// Us[m][L][24] f32; w-local per category, zero-padded.
__global__ __launch_bounds__(256) void usym_kernel(
    const float* __restrict__ U3, const float* __restrict__ U2,
    const float* __restrict__ U1, float* __restrict__ Us){
  int gid = blockIdx.x * 256 + threadIdx.x;
  if (gid >= KPAD * 16) return;
  int m = gid >> 4, L = gid & 15;
  float us[24];
#pragma unroll
  for (int w = 0; w < 24; ++w) us[w] = 0.f;

  if (m < M2B){
    int p = m >> 4, k = m & 15;
    int i = 0, rem = p; while (rem >= 16 - i){ rem -= 16 - i; ++i; }
    int j = i + rem;
    const float* r0 = &U3[((((size_t)L*16 + i)*16 + j)*16 + k)*23];
    if (i < j){
      const float* r1 = &U3[((((size_t)L*16 + j)*16 + i)*16 + k)*23];
#pragma unroll
      for (int w = 0; w < 23; ++w) us[w] = r0[w] + r1[w];
    } else {
#pragma unroll
      for (int w = 0; w < 23; ++w) us[w] = r0[w];
    }
  } else if (m < M1B){
    int p = m - M2B;
    int i = 0, rem = p; while (rem >= 16 - i){ rem -= 16 - i; ++i; }
    int j = i + rem;
#pragma unroll
    for (int w = 0; w < 5; ++w){
      float v = U2[(((size_t)L*16 + i)*16 + j)*5 + w];
      if (i < j) v += U2[(((size_t)L*16 + j)*16 + i)*5 + w];
      us[w] = v;
    }
  } else if (m < KTOT){
    int i = m - M1B;
    us[0] = U1[((size_t)L*16 + i)*2 + 0];
    us[1] = U1[((size_t)L*16 + i)*2 + 1];
  }

  float4* dst = (float4*)(Us + ((size_t)m*16 + L)*24);
#pragma unroll
  for (int q = 0; q < 6; ++q) dst[q] = ((const float4*)us)[q];
}

// ---------------- fold: Bbuf[e][c][s][l][r] = half2{A(m0),A(m0+1)} ----------------
// All register-array indices compile-time (no scratch). WL rows: 0..22=W3,
// 23..27=W2, 28..29=W1, 30..32=zero pad (for wbase=28,w<5 reads).
__global__ __launch_bounds__(256) void fold_kernel(
    const float* __restrict__ Us, const float* __restrict__ W3,
    const float* __restrict__ W2, const float* __restrict__ W1,
    unsigned int* __restrict__ Bbuf, int CB, int CN){
  int s = blockIdx.x, e = blockIdx.y;
  int tid = threadIdx.x;
  int l = tid >> 2, r = tid & 3, g = l >> 4, L = l & 15;
  int m0 = 32*s + 8*g + 2*r;

  __shared__ float WL[33][CCH];
  for (int t = tid; t < 33*CCH; t += 256){
    int row = t >> 6, cc = t & 63;
    float v = 0.f;
    if (row < 23)      v = W3[((size_t)e*23 + row)*CCH + cc];
    else if (row < 28) v = W2[((size_t)e*5 + (row-23))*CCH + cc];
    else if (row < 30) v = W1[((size_t)e*2 + (row-28))*CCH + cc];
    WL[row][cc] = v;
  }
  __syncthreads();

  const float4* s0 = (const float4*)(Us + ((size_t)m0*16 + L)*24);
  const float4* s1 = (const float4*)(Us + ((size_t)(m0+1)*16 + L)*24);

  size_t obase = (((size_t)(e*CN + 0)*NSTEP + s)*64 + l)*4 + r;
  const size_t ostride = (size_t)NSTEP*64*4;

  if (s < 68){
    // pure order-3: 23 weights, static indices
    float u0[24], u1[24];
#pragma unroll
    for (int q = 0; q < 6; ++q){ ((float4*)u0)[q] = s0[q]; ((float4*)u1)[q] = s1[q]; }
#pragma unroll 4
    for (int cc = 0; cc < CN; ++cc){
      int c = CB + cc;
      float a0 = 0.f, a1 = 0.f;
#pragma unroll
      for (int w = 0; w < 23; ++w){
        float wv = WL[w][c];
        a0 += u0[w]*wv; a1 += u1[w]*wv;
      }
      union { __half2 h; unsigned int u; } hu;
      hu.h = __halves2half2(__float2half(a0), __float2half(a1));
      Bbuf[obase + (size_t)cc*ostride] = hu.u;
    }
  } else {
    // order-2 / order-1 / pad: 5 slots, runtime wbase only indexes LDS
    float u0[8], u1[8];
    ((float4*)u0)[0] = s0[0]; ((float4*)u0)[1] = s0[1];
    ((float4*)u1)[0] = s1[0]; ((float4*)u1)[1] = s1[1];
    int wbase = (m0 < M1B) ? 23 : 28;
#pragma unroll 4
    for (int cc = 0; cc < CN; ++cc){
      int c = CB + cc;
      float a0 = 0.f, a1 = 0.f;
#pragma unroll
      for (int w = 0; w < 5; ++w){
        float wv = WL[wbase + w][c];
        a0 += u0[w]*wv; a1 += u1[w]*wv;
      }
      union { __half2 h; unsigned int u; } hu;
      hu.h = __halves2half2(__float2half(a0), __float2half(a1));
      Bbuf[obase + (size_t)cc*ostride] = hu.u;
    }
  }
}

// ---------------- legacy prep (fallback when ws too small) ----------------
__global__ __launch_bounds__(256) void prep_kernel(
    const float* __restrict__ U3, const float* __restrict__ U2,
    const float* __restrict__ U1, const float* __restrict__ W3,
    const float* __restrict__ W2, const float* __restrict__ W1,
    unsigned int* __restrict__ Bbuf, int CB, int CN){
  int s = blockIdx.x, e = blockIdx.y, cz = blockIdx.z;
  int tid = threadIdx.x;
  int l = tid >> 2, r = tid & 3;
  int g = l >> 4, L = l & 15;
  int m0 = 32*s + 8*g + 2*r;

  __shared__ float WL[30][16];
  {
    int cbase = CB + cz*16;
    for (int t = tid; t < 30*16; t += 256){
      int row = t >> 4, cc = t & 15;
      float v;
      if (row < 23)      v = W3[((size_t)e*23 + row)*CCH + cbase + cc];
      else if (row < 28) v = W2[((size_t)e*5 + (row-23))*CCH + cbase + cc];
      else               v = W1[((size_t)e*2 + (row-28))*CCH + cbase + cc];
      WL[row][cc] = v;
    }
  }
  __syncthreads();

  float us0[23], us1[23];
#pragma unroll
  for (int w = 0; w < 23; ++w){ us0[w] = 0.f; us1[w] = 0.f; }

  auto gather = [&](int m, float (&us)[23]) -> int {
    if (m >= KTOT) return 0;
    if (m >= M1B){
      int i = m - M1B;
#pragma unroll
      for (int w = 0; w < 2; ++w) us[w] = U1[((size_t)L*16 + i)*2 + w];
      return 1;
    }
    if (m >= M2B){
      int p = m - M2B;
      int i = 0, rem = p; while (rem >= 16-i){ rem -= 16-i; ++i; }
      int j = i + rem;
#pragma unroll
      for (int w = 0; w < 5; ++w){
        float v = U2[(((size_t)L*16 + i)*16 + j)*5 + w];
        if (i < j) v += U2[(((size_t)L*16 + j)*16 + i)*5 + w];
        us[w] = v;
      }
      return 2;
    }
    int p = m >> 4, k = m & 15;
    int i = 0, rem = p; while (rem >= 16-i){ rem -= 16-i; ++i; }
    int j = i + rem;
#pragma unroll
    for (int w = 0; w < 23; ++w){
      float v = U3[((((size_t)L*16 + i)*16 + j)*16 + k)*23 + w];
      if (i < j) v += U3[((((size_t)L*16 + j)*16 + i)*16 + k)*23 + w];
      us[w] = v;
    }
    return 3;
  };

  int cat = gather(m0, us0);
  (void)gather(m0 + 1, us1);

  for (int cc = 0; cc < 16; ++cc){
    float a0 = 0.f, a1 = 0.f;
    if (cat == 3){
#pragma unroll
      for (int w = 0; w < 23; ++w){ float wv = WL[w][cc]; a0 += us0[w]*wv; a1 += us1[w]*wv; }
    } else if (cat == 2){
#pragma unroll
      for (int w = 0; w < 5; ++w){ float wv = WL[23+w][cc]; a0 += us0[w]*wv; a1 += us1[w]*wv; }
    } else if (cat == 1){
#pragma unroll
      for (int w = 0; w < 2; ++w){ float wv = WL[28+w][cc]; a0 += us0[w]*wv; a1 += us1[w]*wv; }
    }
    union { __half2 h; unsigned int u; } hu;
    hu.h = __halves2half2(__float2half(a0), __float2half(a1));
    int cl = cz*16 + cc;
    Bbuf[(((size_t)(e*CN + cl)*NSTEP + s)*64 + l)*4 + r] = hu.u;
  }
}

// ---------------- main: per-wave 32-atom x K GEMM via MFMA ----------------
// 1-D grid = NE*CN*16 blocks; XCD swizzle pins each (e,c) panel to one XCD.
__global__ __launch_bounds__(256) void main_kernel(
    const float* __restrict__ x, const int* __restrict__ counts,
    const int* __restrict__ bins, const uint4* __restrict__ Bbuf,
    float* __restrict__ out, int CB, int CN){
  int lane = threadIdx.x & 63;
  int wid  = threadIdx.x >> 6;
  int d = blockIdx.x;
  int xcd = d & 7, q = d >> 3;
  int pg = q >> 4, sb = q & 15;
  int p = xcd + 8*pg;                 // panel id, all 16 blocks of a panel on one XCD
  int e = p / CN, cl = p % CN;
  int slot = sb*4 + wid;              // 0..63
  int cnt = counts[e];
  if (slot * 32 >= cnt) return;
  int c = CB + cl;

  int aL = slot*32 + (lane & 15);
  int aH = aL + 16;
  int nL = (aL < cnt) ? bins[e*NATOMS + aL] : -1;
  int nH = (aH < cnt) ? bins[e*NATOMS + aH] : -1;

  float xL[16], xH[16];
#pragma unroll
  for (int i = 0; i < 16; ++i){
    xL[i] = (nL >= 0) ? x[((size_t)nL*16 + i)*CCH + c] : 0.f;
    xH[i] = (nH >= 0) ? x[((size_t)nH*16 + i)*CCH + c] : 0.f;
  }

  bool hi_half = (lane & 16) != 0;
  __half2 xselL[4], xselH[4];
#pragma unroll
  for (int q2 = 0; q2 < 4; ++q2){
    int b0 = (hi_half ? 8 : 0) + 2*q2;
    xselL[q2] = __halves2half2(__float2half(xL[b0]), __float2half(xL[b0+1]));
    xselH[q2] = __halves2half2(__float2half(xH[b0]), __float2half(xH[b0+1]));
  }
  bool gsel = (lane & 32) != 0;

  const uint4* Bp = Bbuf + ((size_t)(e*CN + cl))*NSTEP*64 + lane;

  f32x4 accL = {0.f,0.f,0.f,0.f}, accH = {0.f,0.f,0.f,0.f};
  uint4 buf0 = Bp[0];
  uint4 buf1 = Bp[64];
  uint4 buf2 = Bp[128];
  uint4 buf3 = Bp[192];

  sfor<0, NSTEP>([&](auto sc){
    constexpr int s = decltype(sc)::value;
    constexpr int slt = s & 3;
    uint4 cur;
    if constexpr (slt == 0) cur = buf0;
    else if constexpr (slt == 1) cur = buf1;
    else if constexpr (slt == 2) cur = buf2;
    else cur = buf3;
    if constexpr (s + 4 < NSTEP){
      if constexpr (slt == 0) buf0 = Bp[(size_t)(s+4)*64];
      else if constexpr (slt == 1) buf1 = Bp[(size_t)(s+4)*64];
      else if constexpr (slt == 2) buf2 = Bp[(size_t)(s+4)*64];
      else buf3 = Bp[(size_t)(s+4)*64];
    }

    f16x8 afL, afH;
    if constexpr (32*(s+1) <= K3DIM){           // pure order-3 step
      constexpr int p0 = 2*s, p1 = 2*s + 1;
      constexpr int iA = pair_i(p0), jA = pair_j(p0);
      constexpr int iB = pair_i(p1), jB = pair_j(p1);
      float pAL = xL[iA]*xL[jA], pBL = xL[iB]*xL[jB];
      float pAH = xH[iA]*xH[jA], pBH = xH[iB]*xH[jB];
      __half2 pvL = __float2half2_rn(gsel ? pBL : pAL);
      __half2 pvH = __float2half2_rn(gsel ? pBH : pAH);
      union { __half2 h[4]; f16x8 v; } uL, uH;
#pragma unroll
      for (int q2 = 0; q2 < 4; ++q2){
        uL.h[q2] = __hmul2(pvL, xselL[q2]);
        uH.h[q2] = __hmul2(pvH, xselH[q2]);
      }
      afL = uL.v; afH = uH.v;
    } else {                                     // tail: order-2/1/pad
      int g = (lane >> 4) & 3;
      if      (g == 0){ afL = tailfrag<s,0>(xL); afH = tailfrag<s,0>(xH); }
      else if (g == 1){ afL = tailfrag<s,1>(xL); afH = tailfrag<s,1>(xH); }
      else if (g == 2){ afL = tailfrag<s,2>(xL); afH = tailfrag<s,2>(xH); }
      else            { afL = tailfrag<s,3>(xL); afH = tailfrag<s,3>(xH); }
    }
    union { uint4 u; f16x8 v; } bc; bc.u = cur;
    accL = __builtin_amdgcn_mfma_f32_16x16x32_f16(afL, bc.v, accL, 0, 0, 0);
    accH = __builtin_amdgcn_mfma_f32_16x16x32_f16(afH, bc.v, accH, 0, 0, 0);
  });

  int gp = lane >> 4, L = lane & 15;
#pragma unroll
  for (int r = 0; r < 4; ++r){
    int pl = slot*32 + 4*gp + r;
    if (pl < cnt){ int n = bins[e*NATOMS + pl]; out[((size_t)n*16 + L)*CCH + c] = accL[r]; }
    int ph = pl + 16;
    if (ph < cnt){ int n = bins[e*NATOMS + ph]; out[((size_t)n*16 + L)*CCH + c] = accH[r]; }
  }
}

extern "C" void kernel_launch(void* const* d_in, const int* in_sizes, int n_in,
                              void* d_out, int out_size, void* d_ws, size_t ws_size,
                              hipStream_t stream){
  const float* x   = (const float*)d_in[0];
  const int* types = (const int*)d_in[1];
  const float* U3  = (const float*)d_in[2];
  const float* U2  = (const float*)d_in[3];
  const float* U1  = (const float*)d_in[4];
  const float* W3  = (const float*)d_in[5];
  const float* W2  = (const float*)d_in[6];
  const float* W1  = (const float*)d_in[7];
  float* out = (float*)d_out;

  char* ws = (char*)d_ws;
  int* counts = (int*)ws;                        // 256 B
  int* bins   = (int*)(ws + 256);                // 32 KB -> offset 33280 aligned
  const size_t usOff   = 33280;
  const size_t usBytes = (size_t)KPAD * 16 * 24 * 4;          // 3,588,096
  const size_t bbOff   = (usOff + usBytes + 511) & ~(size_t)511;
  const size_t bbBytes = (size_t)NE * 64 * NSTEP * 64 * 16;   // 19,136,512

  hipMemsetAsync(counts, 0, NE * sizeof(int), stream);
  bin_kernel<<<(NATOMS + 255) / 256, 256, 0, stream>>>(types, counts, bins);

  if (ws_size >= bbOff + bbBytes){
    // fast path: usym once + coalesced fold
    float* Us = (float*)(ws + usOff);
    unsigned int* Bbuf = (unsigned int*)(ws + bbOff);
    usym_kernel<<<(KPAD*16 + 255)/256, 256, 0, stream>>>(U3, U2, U1, Us);
    fold_kernel<<<dim3(NSTEP, NE), 256, 0, stream>>>(Us, W3, W2, W1, Bbuf, 0, 64);
    main_kernel<<<dim3(NE*64*16), 256, 0, stream>>>(x, counts, bins, (const uint4*)Bbuf, out, 0, 64);
  } else if (ws_size >= 33280 + bbBytes){
    unsigned int* Bbuf = (unsigned int*)(ws + 33280);
    prep_kernel<<<dim3(NSTEP, NE, 4), 256, 0, stream>>>(U3,U2,U1,W3,W2,W1,Bbuf,0,64);
    main_kernel<<<dim3(NE*64*16), 256, 0, stream>>>(x, counts, bins, (const uint4*)Bbuf, out, 0, 64);
  } else {
    unsigned int* Bbuf = (unsigned int*)(ws + 33280);
    prep_kernel<<<dim3(NSTEP, NE, 2), 256, 0, stream>>>(U3,U2,U1,W3,W2,W1,Bbuf,0,32);
    main_kernel<<<dim3(NE*32*16), 256, 0, stream>>>(x, counts, bins, (const uint4*)Bbuf, out, 0, 32);
    prep_kernel<<<dim3(NSTEP, NE, 2), 256, 0, stream>>>(U3,U2,U1,W3,W2,W1,Bbuf,32,32);
    main_kernel<<<dim3(NE*32*16), 256, 0, stream>>>(x, counts, bins, (const uint4*)Bbuf, out, 32, 32);
  }
}

// Round 5
// 112.499 us; speedup vs baseline: 14.9309x; 1.0837x over previous
//
#include <hip/hip_runtime.h>
#include <hip/hip_fp16.h>

#define NATOMS 2048
#define CCH    64
#define NE     4

#define NP    136     // #{i<=j} pairs over 16
#define K3DIM 2176    // 136*16 inflated order-3 K
#define M2B   2176
#define M1B   2312
#define KTOT  2328
#define KPAD  2336
#define NSTEP 73      // KPAD/32
#define MAXSLOTS 68   // sum ceil(cnt_e/32) <= 64+4

typedef _Float16 f16x8 __attribute__((ext_vector_type(8)));
typedef float f32x4 __attribute__((ext_vector_type(4)));

__host__ __device__ constexpr int pair_i(int p){ int i=0, rem=p; while (rem >= 16-i){ rem -= 16-i; ++i; } return i; }
__host__ __device__ constexpr int pair_j(int p){ int i=0, rem=p; while (rem >= 16-i){ rem -= 16-i; ++i; } return i+rem; }

template<int N> struct IC { static constexpr int value = N; };
template<int S, int E, typename F> __device__ __forceinline__ void sfor(F&& f){
  if constexpr (S < E){ f(IC<S>{}); sfor<S+1,E>(f); }
}

// monomial value for tail region (m >= M2B), compile-time M
template<int M> __device__ __forceinline__ float monval(const float (&xf)[16]){
  if constexpr (M >= KTOT) { (void)xf; return 0.f; }
  else if constexpr (M >= M1B) return xf[M - M1B];
  else {
    constexpr int p  = M - M2B;
    constexpr int i0 = pair_i(p), j0 = pair_j(p);
    return xf[i0] * xf[j0];
  }
}

template<int S, int G> __device__ __forceinline__ f16x8 tailfrag(const float (&xf)[16]){
  union { __half2 h[4]; f16x8 v; } u;
#define TE(E2) { float lo = monval<32*S+8*G+2*E2>(xf); float hi = monval<32*S+8*G+2*E2+1>(xf); \
                 u.h[E2] = __halves2half2(__float2half(lo), __float2half(hi)); }
  TE(0) TE(1) TE(2) TE(3)
#undef TE
  return u.v;
}

// ---------------- binning ----------------
__global__ void bin_kernel(const int* __restrict__ types, int* counts, int* bins){
  int n = blockIdx.x * blockDim.x + threadIdx.x;
  if (n < NATOMS){
    int t = types[n];
    int pos = atomicAdd(&counts[t], 1);
    bins[t * NATOMS + pos] = n;
  }
}

// ---------------- slot table: (e, local_base) per padded 32-atom slot ----------------
__global__ void table_kernel(const int* __restrict__ counts, int* tab_e, int* tab_b, int* nslots){
  if (threadIdx.x == 0 && blockIdx.x == 0){
    int ns = 0;
    for (int e = 0; e < NE; ++e){
      int c = counts[e];
      for (int b = 0; b < c; b += 32){ tab_e[ns] = e; tab_b[ns] = b; ++ns; }
    }
    *nslots = ns;
  }
}

// ---------------- usym: symmetrized CG rows, 6-way parallel per (m,L) ----------------
// Us[m][L][24] f32; thread computes float4 chunk w = 4q..4q+3.
__global__ __launch_bounds__(256) void usym_kernel(
    const float* __restrict__ U3, const float* __restrict__ U2,
    const float* __restrict__ U1, float* __restrict__ Us){
  int gid = blockIdx.x * 256 + threadIdx.x;
  if (gid >= KPAD * 16 * 6) return;
  int q = gid % 6;
  int t2 = gid / 6;
  int L = t2 & 15, m = t2 >> 4;
  int w0 = q * 4;

  float v[4] = {0.f, 0.f, 0.f, 0.f};
  if (m < M2B){
    int p = m >> 4, k = m & 15;
    int i = 0, rem = p; while (rem >= 16 - i){ rem -= 16 - i; ++i; }
    int j = i + rem;
    const float* r0 = &U3[((((size_t)L*16 + i)*16 + j)*16 + k)*23];
    if (i < j){
      const float* r1 = &U3[((((size_t)L*16 + j)*16 + i)*16 + k)*23];
#pragma unroll
      for (int t = 0; t < 4; ++t){ int w = w0 + t; if (w < 23) v[t] = r0[w] + r1[w]; }
    } else {
#pragma unroll
      for (int t = 0; t < 4; ++t){ int w = w0 + t; if (w < 23) v[t] = r0[w]; }
    }
  } else if (m < M1B){
    if (w0 < 5){
      int p = m - M2B;
      int i = 0, rem = p; while (rem >= 16 - i){ rem -= 16 - i; ++i; }
      int j = i + rem;
#pragma unroll
      for (int t = 0; t < 4; ++t){
        int w = w0 + t;
        if (w < 5){
          float s = U2[(((size_t)L*16 + i)*16 + j)*5 + w];
          if (i < j) s += U2[(((size_t)L*16 + j)*16 + i)*5 + w];
          v[t] = s;
        }
      }
    }
  } else if (m < KTOT){
    if (w0 == 0){
      int i = m - M1B;
      v[0] = U1[((size_t)L*16 + i)*2 + 0];
      v[1] = U1[((size_t)L*16 + i)*2 + 1];
    }
  }
  float4* dst = (float4*)(Us + ((size_t)m*16 + L)*24 + w0);
  *dst = make_float4(v[0], v[1], v[2], v[3]);
}

// ---------------- fold: Bbuf[e][c][s][l][r] = half2{A(m0),A(m0+1)} ----------------
__global__ __launch_bounds__(256) void fold_kernel(
    const float* __restrict__ Us, const float* __restrict__ W3,
    const float* __restrict__ W2, const float* __restrict__ W1,
    unsigned int* __restrict__ Bbuf, int CB, int CN){
  int s = blockIdx.x, e = blockIdx.y;
  int tid = threadIdx.x;
  int l = tid >> 2, r = tid & 3, g = l >> 4, L = l & 15;
  int m0 = 32*s + 8*g + 2*r;

  __shared__ float WL[33][CCH];
  for (int t = tid; t < 33*CCH; t += 256){
    int row = t >> 6, cc = t & 63;
    float v = 0.f;
    if (row < 23)      v = W3[((size_t)e*23 + row)*CCH + cc];
    else if (row < 28) v = W2[((size_t)e*5 + (row-23))*CCH + cc];
    else if (row < 30) v = W1[((size_t)e*2 + (row-28))*CCH + cc];
    WL[row][cc] = v;
  }
  __syncthreads();

  const float4* s0 = (const float4*)(Us + ((size_t)m0*16 + L)*24);
  const float4* s1 = (const float4*)(Us + ((size_t)(m0+1)*16 + L)*24);

  size_t obase = (((size_t)(e*CN + 0)*NSTEP + s)*64 + l)*4 + r;
  const size_t ostride = (size_t)NSTEP*64*4;

  if (s < 68){
    float u0[24], u1[24];
#pragma unroll
    for (int q = 0; q < 6; ++q){ ((float4*)u0)[q] = s0[q]; ((float4*)u1)[q] = s1[q]; }
#pragma unroll 4
    for (int cc = 0; cc < CN; ++cc){
      int c = CB + cc;
      float a0 = 0.f, a1 = 0.f;
#pragma unroll
      for (int w = 0; w < 23; ++w){
        float wv = WL[w][c];
        a0 += u0[w]*wv; a1 += u1[w]*wv;
      }
      union { __half2 h; unsigned int u; } hu;
      hu.h = __halves2half2(__float2half(a0), __float2half(a1));
      Bbuf[obase + (size_t)cc*ostride] = hu.u;
    }
  } else {
    float u0[8], u1[8];
    ((float4*)u0)[0] = s0[0]; ((float4*)u0)[1] = s0[1];
    ((float4*)u1)[0] = s1[0]; ((float4*)u1)[1] = s1[1];
    int wbase = (m0 < M1B) ? 23 : 28;
#pragma unroll 4
    for (int cc = 0; cc < CN; ++cc){
      int c = CB + cc;
      float a0 = 0.f, a1 = 0.f;
#pragma unroll
      for (int w = 0; w < 5; ++w){
        float wv = WL[wbase + w][c];
        a0 += u0[w]*wv; a1 += u1[w]*wv;
      }
      union { __half2 h; unsigned int u; } hu;
      hu.h = __halves2half2(__float2half(a0), __float2half(a1));
      Bbuf[obase + (size_t)cc*ostride] = hu.u;
    }
  }
}

// ---------------- legacy prep (fallback when ws too small) ----------------
__global__ __launch_bounds__(256) void prep_kernel(
    const float* __restrict__ U3, const float* __restrict__ U2,
    const float* __restrict__ U1, const float* __restrict__ W3,
    const float* __restrict__ W2, const float* __restrict__ W1,
    unsigned int* __restrict__ Bbuf, int CB, int CN){
  int s = blockIdx.x, e = blockIdx.y, cz = blockIdx.z;
  int tid = threadIdx.x;
  int l = tid >> 2, r = tid & 3;
  int g = l >> 4, L = l & 15;
  int m0 = 32*s + 8*g + 2*r;

  __shared__ float WL[30][16];
  {
    int cbase = CB + cz*16;
    for (int t = tid; t < 30*16; t += 256){
      int row = t >> 4, cc = t & 15;
      float v;
      if (row < 23)      v = W3[((size_t)e*23 + row)*CCH + cbase + cc];
      else if (row < 28) v = W2[((size_t)e*5 + (row-23))*CCH + cbase + cc];
      else               v = W1[((size_t)e*2 + (row-28))*CCH + cbase + cc];
      WL[row][cc] = v;
    }
  }
  __syncthreads();

  float us0[23], us1[23];
#pragma unroll
  for (int w = 0; w < 23; ++w){ us0[w] = 0.f; us1[w] = 0.f; }

  auto gather = [&](int m, float (&us)[23]) -> int {
    if (m >= KTOT) return 0;
    if (m >= M1B){
      int i = m - M1B;
#pragma unroll
      for (int w = 0; w < 2; ++w) us[w] = U1[((size_t)L*16 + i)*2 + w];
      return 1;
    }
    if (m >= M2B){
      int p = m - M2B;
      int i = 0, rem = p; while (rem >= 16-i){ rem -= 16-i; ++i; }
      int j = i + rem;
#pragma unroll
      for (int w = 0; w < 5; ++w){
        float v = U2[(((size_t)L*16 + i)*16 + j)*5 + w];
        if (i < j) v += U2[(((size_t)L*16 + j)*16 + i)*5 + w];
        us[w] = v;
      }
      return 2;
    }
    int p = m >> 4, k = m & 15;
    int i = 0, rem = p; while (rem >= 16-i){ rem -= 16-i; ++i; }
    int j = i + rem;
#pragma unroll
    for (int w = 0; w < 23; ++w){
      float v = U3[((((size_t)L*16 + i)*16 + j)*16 + k)*23 + w];
      if (i < j) v += U3[((((size_t)L*16 + j)*16 + i)*16 + k)*23 + w];
      us[w] = v;
    }
    return 3;
  };

  int cat = gather(m0, us0);
  (void)gather(m0 + 1, us1);

  for (int cc = 0; cc < 16; ++cc){
    float a0 = 0.f, a1 = 0.f;
    if (cat == 3){
#pragma unroll
      for (int w = 0; w < 23; ++w){ float wv = WL[w][cc]; a0 += us0[w]*wv; a1 += us1[w]*wv; }
    } else if (cat == 2){
#pragma unroll
      for (int w = 0; w < 5; ++w){ float wv = WL[23+w][cc]; a0 += us0[w]*wv; a1 += us1[w]*wv; }
    } else if (cat == 1){
#pragma unroll
      for (int w = 0; w < 2; ++w){ float wv = WL[28+w][cc]; a0 += us0[w]*wv; a1 += us1[w]*wv; }
    }
    union { __half2 h; unsigned int u; } hu;
    hu.h = __halves2half2(__float2half(a0), __float2half(a1));
    int cl = cz*16 + cc;
    Bbuf[(((size_t)(e*CN + cl)*NSTEP + s)*64 + l)*4 + r] = hu.u;
  }
}

// ---------------- shared MFMA body ----------------
template<int DEPTH>
__device__ __forceinline__ void gemm_body(
    const float (&xL)[16], const float (&xH)[16], const uint4* Bp,
    int lane, f32x4& accL, f32x4& accH){
  bool hi_half = (lane & 16) != 0;
  __half2 xselL[4], xselH[4];
#pragma unroll
  for (int q2 = 0; q2 < 4; ++q2){
    int b0 = (hi_half ? 8 : 0) + 2*q2;
    xselL[q2] = __halves2half2(__float2half(xL[b0]), __float2half(xL[b0+1]));
    xselH[q2] = __halves2half2(__float2half(xH[b0]), __float2half(xH[b0+1]));
  }
  bool gsel = (lane & 32) != 0;

  uint4 buf0 = Bp[0];
  uint4 buf1 = Bp[64];
  uint4 buf2 = Bp[128];
  uint4 buf3 = Bp[192];

  sfor<0, NSTEP>([&](auto sc){
    constexpr int s = decltype(sc)::value;
    constexpr int slt = s & 3;
    uint4 cur;
    if constexpr (slt == 0) cur = buf0;
    else if constexpr (slt == 1) cur = buf1;
    else if constexpr (slt == 2) cur = buf2;
    else cur = buf3;
    if constexpr (s + 4 < NSTEP){
      if constexpr (slt == 0) buf0 = Bp[(size_t)(s+4)*64];
      else if constexpr (slt == 1) buf1 = Bp[(size_t)(s+4)*64];
      else if constexpr (slt == 2) buf2 = Bp[(size_t)(s+4)*64];
      else buf3 = Bp[(size_t)(s+4)*64];
    }

    f16x8 afL, afH;
    if constexpr (32*(s+1) <= K3DIM){
      constexpr int p0 = 2*s, p1 = 2*s + 1;
      constexpr int iA = pair_i(p0), jA = pair_j(p0);
      constexpr int iB = pair_i(p1), jB = pair_j(p1);
      float pAL = xL[iA]*xL[jA], pBL = xL[iB]*xL[jB];
      float pAH = xH[iA]*xH[jA], pBH = xH[iB]*xH[jB];
      __half2 pvL = __float2half2_rn(gsel ? pBL : pAL);
      __half2 pvH = __float2half2_rn(gsel ? pBH : pAH);
      union { __half2 h[4]; f16x8 v; } uL, uH;
#pragma unroll
      for (int q2 = 0; q2 < 4; ++q2){
        uL.h[q2] = __hmul2(pvL, xselL[q2]);
        uH.h[q2] = __hmul2(pvH, xselH[q2]);
      }
      afL = uL.v; afH = uH.v;
    } else {
      int g = (lane >> 4) & 3;
      if      (g == 0){ afL = tailfrag<s,0>(xL); afH = tailfrag<s,0>(xH); }
      else if (g == 1){ afL = tailfrag<s,1>(xL); afH = tailfrag<s,1>(xH); }
      else if (g == 2){ afL = tailfrag<s,2>(xL); afH = tailfrag<s,2>(xH); }
      else            { afL = tailfrag<s,3>(xL); afH = tailfrag<s,3>(xH); }
    }
    union { uint4 u; f16x8 v; } bc; bc.u = cur;
    accL = __builtin_amdgcn_mfma_f32_16x16x32_f16(afL, bc.v, accL, 0, 0, 0);
    accH = __builtin_amdgcn_mfma_f32_16x16x32_f16(afH, bc.v, accH, 0, 0, 0);
  });
}

// ---------------- main2: compacted wave-task grid + 2D XCD tiling ----------------
// grid.x = 1088 = 68 slots x 16 c4-groups, block = 256 = 4 waves = 4 c's.
// XCD tile = (slot-half, c16-group): all 16 c's of an x/out line on one XCD.
__global__ __launch_bounds__(256) void main2_kernel(
    const float* __restrict__ x, const int* __restrict__ counts,
    const int* __restrict__ tab_e, const int* __restrict__ tab_b,
    const int* __restrict__ nslots, const int* __restrict__ bins,
    const uint4* __restrict__ Bbuf, float* __restrict__ out){
  int d = blockIdx.x;
  int q = d >> 3;
  int g16 = (d >> 1) & 3, sh = d & 1;
  int c4 = g16*4 + (q & 3);
  int g  = sh*34 + (q >> 2);
  if (g >= *nslots) return;

  int wid = threadIdx.x >> 6, lane = threadIdx.x & 63;
  int c = c4*4 + wid;
  int e = tab_e[g];
  int b0 = tab_b[g];
  int cnt = counts[e];

  int aL = b0 + (lane & 15);
  int aH = aL + 16;
  int nL = (aL < cnt) ? bins[e*NATOMS + aL] : -1;
  int nH = (aH < cnt) ? bins[e*NATOMS + aH] : -1;

  float xL[16], xH[16];
#pragma unroll
  for (int i = 0; i < 16; ++i){
    xL[i] = (nL >= 0) ? x[((size_t)nL*16 + i)*CCH + c] : 0.f;
    xH[i] = (nH >= 0) ? x[((size_t)nH*16 + i)*CCH + c] : 0.f;
  }

  const uint4* Bp = Bbuf + ((size_t)(e*CCH + c))*NSTEP*64 + lane;
  f32x4 accL = {0.f,0.f,0.f,0.f}, accH = {0.f,0.f,0.f,0.f};
  gemm_body<4>(xL, xH, Bp, lane, accL, accH);

  int gp = lane >> 4, L = lane & 15;
#pragma unroll
  for (int r = 0; r < 4; ++r){
    int pl = b0 + 4*gp + r;
    if (pl < cnt){ int n = bins[e*NATOMS + pl]; out[((size_t)n*16 + L)*CCH + c] = accL[r]; }
    int ph = pl + 16;
    if (ph < cnt){ int n = bins[e*NATOMS + ph]; out[((size_t)n*16 + L)*CCH + c] = accH[r]; }
  }
}

// ---------------- legacy main (fallback) ----------------
__global__ __launch_bounds__(256) void main_kernel(
    const float* __restrict__ x, const int* __restrict__ counts,
    const int* __restrict__ bins, const uint4* __restrict__ Bbuf,
    float* __restrict__ out, int CB, int CN){
  int lane = threadIdx.x & 63;
  int wid  = threadIdx.x >> 6;
  int d = blockIdx.x;
  int xcd = d & 7, q = d >> 3;
  int pg = q >> 4, sb = q & 15;
  int p = xcd + 8*pg;
  int e = p / CN, cl = p % CN;
  int slot = sb*4 + wid;
  int cnt = counts[e];
  if (slot * 32 >= cnt) return;
  int c = CB + cl;

  int aL = slot*32 + (lane & 15);
  int aH = aL + 16;
  int nL = (aL < cnt) ? bins[e*NATOMS + aL] : -1;
  int nH = (aH < cnt) ? bins[e*NATOMS + aH] : -1;

  float xL[16], xH[16];
#pragma unroll
  for (int i = 0; i < 16; ++i){
    xL[i] = (nL >= 0) ? x[((size_t)nL*16 + i)*CCH + c] : 0.f;
    xH[i] = (nH >= 0) ? x[((size_t)nH*16 + i)*CCH + c] : 0.f;
  }

  const uint4* Bp = Bbuf + ((size_t)(e*CN + cl))*NSTEP*64 + lane;
  f32x4 accL = {0.f,0.f,0.f,0.f}, accH = {0.f,0.f,0.f,0.f};
  gemm_body<4>(xL, xH, Bp, lane, accL, accH);

  int gp = lane >> 4, L = lane & 15;
#pragma unroll
  for (int r = 0; r < 4; ++r){
    int pl = slot*32 + 4*gp + r;
    if (pl < cnt){ int n = bins[e*NATOMS + pl]; out[((size_t)n*16 + L)*CCH + c] = accL[r]; }
    int ph = pl + 16;
    if (ph < cnt){ int n = bins[e*NATOMS + ph]; out[((size_t)n*16 + L)*CCH + c] = accH[r]; }
  }
}

extern "C" void kernel_launch(void* const* d_in, const int* in_sizes, int n_in,
                              void* d_out, int out_size, void* d_ws, size_t ws_size,
                              hipStream_t stream){
  const float* x   = (const float*)d_in[0];
  const int* types = (const int*)d_in[1];
  const float* U3  = (const float*)d_in[2];
  const float* U2  = (const float*)d_in[3];
  const float* U1  = (const float*)d_in[4];
  const float* W3  = (const float*)d_in[5];
  const float* W2  = (const float*)d_in[6];
  const float* W1  = (const float*)d_in[7];
  float* out = (float*)d_out;

  char* ws = (char*)d_ws;
  int* counts  = (int*)ws;               // +0    (16 B)
  int* nslots  = (int*)(ws + 16);        // +16
  int* tab_e   = (int*)(ws + 64);        // +64   (272 B)
  int* tab_b   = (int*)(ws + 384);       // +384  (272 B)
  int* bins    = (int*)(ws + 1024);      // +1024 (32 KB) -> ends 33792

  const size_t usOff   = 33792;                               // 512-aligned
  const size_t usBytes = (size_t)KPAD * 16 * 24 * 4;          // 3,588,096
  const size_t bbOff   = usOff + usBytes;                     // 3,621,888 (512-aligned)
  const size_t bbBytes = (size_t)NE * 64 * NSTEP * 64 * 16;   // 19,136,512

  hipMemsetAsync(counts, 0, NE * sizeof(int), stream);
  bin_kernel<<<(NATOMS + 255) / 256, 256, 0, stream>>>(types, counts, bins);
  table_kernel<<<1, 64, 0, stream>>>(counts, tab_e, tab_b, nslots);

  if (ws_size >= bbOff + bbBytes){
    float* Us = (float*)(ws + usOff);
    unsigned int* Bbuf = (unsigned int*)(ws + bbOff);
    usym_kernel<<<(KPAD*16*6 + 255)/256, 256, 0, stream>>>(U3, U2, U1, Us);
    fold_kernel<<<dim3(NSTEP, NE), 256, 0, stream>>>(Us, W3, W2, W1, Bbuf, 0, 64);
    main2_kernel<<<dim3(MAXSLOTS*16), 256, 0, stream>>>(x, counts, tab_e, tab_b, nslots,
                                                        bins, (const uint4*)Bbuf, out);
  } else if (ws_size >= 34816 + bbBytes){
    unsigned int* Bbuf = (unsigned int*)(ws + 34816);
    prep_kernel<<<dim3(NSTEP, NE, 4), 256, 0, stream>>>(U3,U2,U1,W3,W2,W1,Bbuf,0,64);
    main_kernel<<<dim3(NE*64*16), 256, 0, stream>>>(x, counts, bins, (const uint4*)Bbuf, out, 0, 64);
  } else {
    unsigned int* Bbuf = (unsigned int*)(ws + 34816);
    prep_kernel<<<dim3(NSTEP, NE, 2), 256, 0, stream>>>(U3,U2,U1,W3,W2,W1,Bbuf,0,32);
    main_kernel<<<dim3(NE*32*16), 256, 0, stream>>>(x, counts, bins, (const uint4*)Bbuf, out, 0, 32);
    prep_kernel<<<dim3(NSTEP, NE, 2), 256, 0, stream>>>(U3,U2,U1,W3,W2,W1,Bbuf,32,32);
    main_kernel<<<dim3(NE*32*16), 256, 0, stream>>>(x, counts, bins, (const uint4*)Bbuf, out, 32, 32);
  }
}

// Round 6
// 89.809 us; speedup vs baseline: 18.7030x; 1.2526x over previous
//
#include <hip/hip_runtime.h>
#include <hip/hip_fp16.h>

#define NATOMS 2048
#define CCH    64
#define NE     4

#define NP    136     // #{i<=j} pairs over 16
#define K3DIM 2176    // 136*16 inflated order-3 K
#define M2B   2176
#define M1B   2312
#define KTOT  2328
#define KPAD  2336
#define NSTEP 73      // KPAD/32
#define MAXSLOTS 68   // sum ceil(cnt_e/32) <= 64+4

typedef _Float16 f16x8 __attribute__((ext_vector_type(8)));
typedef float f32x4 __attribute__((ext_vector_type(4)));

__host__ __device__ constexpr int pair_i(int p){ int i=0, rem=p; while (rem >= 16-i){ rem -= 16-i; ++i; } return i; }
__host__ __device__ constexpr int pair_j(int p){ int i=0, rem=p; while (rem >= 16-i){ rem -= 16-i; ++i; } return i+rem; }

template<int N> struct IC { static constexpr int value = N; };
template<int S, int E, typename F> __device__ __forceinline__ void sfor(F&& f){
  if constexpr (S < E){ f(IC<S>{}); sfor<S+1,E>(f); }
}

// monomial value for tail region (m >= M2B), compile-time M
template<int M> __device__ __forceinline__ float monval(const float (&xf)[16]){
  if constexpr (M >= KTOT) { (void)xf; return 0.f; }
  else if constexpr (M >= M1B) return xf[M - M1B];
  else {
    constexpr int p  = M - M2B;
    constexpr int i0 = pair_i(p), j0 = pair_j(p);
    return xf[i0] * xf[j0];
  }
}

template<int S, int G> __device__ __forceinline__ f16x8 tailfrag(const float (&xf)[16]){
  union { __half2 h[4]; f16x8 v; } u;
#define TE(E2) { float lo = monval<32*S+8*G+2*E2>(xf); float hi = monval<32*S+8*G+2*E2+1>(xf); \
                 u.h[E2] = __halves2half2(__float2half(lo), __float2half(hi)); }
  TE(0) TE(1) TE(2) TE(3)
#undef TE
  return u.v;
}

// ---------------- binning ----------------
__global__ void bin_kernel(const int* __restrict__ types, int* counts, int* bins){
  int n = blockIdx.x * blockDim.x + threadIdx.x;
  if (n < NATOMS){
    int t = types[n];
    int pos = atomicAdd(&counts[t], 1);
    bins[t * NATOMS + pos] = n;
  }
}

// ---------------- usym: symmetrized CG rows, 6-way parallel per (m,L) ----------------
// Us[m][L][24] f32; thread computes float4 chunk w = 4q..4q+3.
__global__ __launch_bounds__(256) void usym_kernel(
    const float* __restrict__ U3, const float* __restrict__ U2,
    const float* __restrict__ U1, float* __restrict__ Us){
  int gid = blockIdx.x * 256 + threadIdx.x;
  if (gid >= KPAD * 16 * 6) return;
  int q = gid % 6;
  int t2 = gid / 6;
  int L = t2 & 15, m = t2 >> 4;
  int w0 = q * 4;

  float v[4] = {0.f, 0.f, 0.f, 0.f};
  if (m < M2B){
    int p = m >> 4, k = m & 15;
    int i = 0, rem = p; while (rem >= 16 - i){ rem -= 16 - i; ++i; }
    int j = i + rem;
    const float* r0 = &U3[((((size_t)L*16 + i)*16 + j)*16 + k)*23];
    if (i < j){
      const float* r1 = &U3[((((size_t)L*16 + j)*16 + i)*16 + k)*23];
#pragma unroll
      for (int t = 0; t < 4; ++t){ int w = w0 + t; if (w < 23) v[t] = r0[w] + r1[w]; }
    } else {
#pragma unroll
      for (int t = 0; t < 4; ++t){ int w = w0 + t; if (w < 23) v[t] = r0[w]; }
    }
  } else if (m < M1B){
    if (w0 < 5){
      int p = m - M2B;
      int i = 0, rem = p; while (rem >= 16 - i){ rem -= 16 - i; ++i; }
      int j = i + rem;
#pragma unroll
      for (int t = 0; t < 4; ++t){
        int w = w0 + t;
        if (w < 5){
          float s = U2[(((size_t)L*16 + i)*16 + j)*5 + w];
          if (i < j) s += U2[(((size_t)L*16 + j)*16 + i)*5 + w];
          v[t] = s;
        }
      }
    }
  } else if (m < KTOT){
    if (w0 == 0){
      int i = m - M1B;
      v[0] = U1[((size_t)L*16 + i)*2 + 0];
      v[1] = U1[((size_t)L*16 + i)*2 + 1];
    }
  }
  float4* dst = (float4*)(Us + ((size_t)m*16 + L)*24 + w0);
  *dst = make_float4(v[0], v[1], v[2], v[3]);
}

// ---------------- fold: Bbuf[e][c][s][l][r] = half2{A(m0),A(m0+1)} ----------------
// grid (NSTEP, NE, 4): z splits the 64 channels into 4 groups of 16.
__global__ __launch_bounds__(256) void fold_kernel(
    const float* __restrict__ Us, const float* __restrict__ W3,
    const float* __restrict__ W2, const float* __restrict__ W1,
    unsigned int* __restrict__ Bbuf){
  int s = blockIdx.x, e = blockIdx.y;
  int ccBase = blockIdx.z * 16;
  int tid = threadIdx.x;
  int l = tid >> 2, r = tid & 3, g = l >> 4, L = l & 15;
  int m0 = 32*s + 8*g + 2*r;

  __shared__ float WL[33][16];
  for (int t = tid; t < 33*16; t += 256){
    int row = t >> 4, cc = t & 15;
    int c = ccBase + cc;
    float v = 0.f;
    if (row < 23)      v = W3[((size_t)e*23 + row)*CCH + c];
    else if (row < 28) v = W2[((size_t)e*5 + (row-23))*CCH + c];
    else if (row < 30) v = W1[((size_t)e*2 + (row-28))*CCH + c];
    WL[row][cc] = v;
  }
  __syncthreads();

  const float4* s0 = (const float4*)(Us + ((size_t)m0*16 + L)*24);
  const float4* s1 = (const float4*)(Us + ((size_t)(m0+1)*16 + L)*24);

  const size_t ostride = (size_t)NSTEP*64*4;
  size_t obase = (((size_t)(e*CCH + ccBase)*NSTEP + s)*64 + l)*4 + r;

  if (s < 68){
    float u0[24], u1[24];
#pragma unroll
    for (int q = 0; q < 6; ++q){ ((float4*)u0)[q] = s0[q]; ((float4*)u1)[q] = s1[q]; }
#pragma unroll 4
    for (int cc = 0; cc < 16; ++cc){
      float a0 = 0.f, a1 = 0.f;
#pragma unroll
      for (int w = 0; w < 23; ++w){
        float wv = WL[w][cc];
        a0 += u0[w]*wv; a1 += u1[w]*wv;
      }
      union { __half2 h; unsigned int u; } hu;
      hu.h = __halves2half2(__float2half(a0), __float2half(a1));
      Bbuf[obase + (size_t)cc*ostride] = hu.u;
    }
  } else {
    float u0[8], u1[8];
    ((float4*)u0)[0] = s0[0]; ((float4*)u0)[1] = s0[1];
    ((float4*)u1)[0] = s1[0]; ((float4*)u1)[1] = s1[1];
    int wbase = (m0 < M1B) ? 23 : 28;
#pragma unroll 4
    for (int cc = 0; cc < 16; ++cc){
      float a0 = 0.f, a1 = 0.f;
#pragma unroll
      for (int w = 0; w < 5; ++w){
        float wv = WL[wbase + w][cc];
        a0 += u0[w]*wv; a1 += u1[w]*wv;
      }
      union { __half2 h; unsigned int u; } hu;
      hu.h = __halves2half2(__float2half(a0), __float2half(a1));
      Bbuf[obase + (size_t)cc*ostride] = hu.u;
    }
  }
}

// ---------------- legacy prep (fallback when ws too small) ----------------
__global__ __launch_bounds__(256) void prep_kernel(
    const float* __restrict__ U3, const float* __restrict__ U2,
    const float* __restrict__ U1, const float* __restrict__ W3,
    const float* __restrict__ W2, const float* __restrict__ W1,
    unsigned int* __restrict__ Bbuf, int CB, int CN){
  int s = blockIdx.x, e = blockIdx.y, cz = blockIdx.z;
  int tid = threadIdx.x;
  int l = tid >> 2, r = tid & 3;
  int g = l >> 4, L = l & 15;
  int m0 = 32*s + 8*g + 2*r;

  __shared__ float WL[30][16];
  {
    int cbase = CB + cz*16;
    for (int t = tid; t < 30*16; t += 256){
      int row = t >> 4, cc = t & 15;
      float v;
      if (row < 23)      v = W3[((size_t)e*23 + row)*CCH + cbase + cc];
      else if (row < 28) v = W2[((size_t)e*5 + (row-23))*CCH + cbase + cc];
      else               v = W1[((size_t)e*2 + (row-28))*CCH + cbase + cc];
      WL[row][cc] = v;
    }
  }
  __syncthreads();

  float us0[23], us1[23];
#pragma unroll
  for (int w = 0; w < 23; ++w){ us0[w] = 0.f; us1[w] = 0.f; }

  auto gather = [&](int m, float (&us)[23]) -> int {
    if (m >= KTOT) return 0;
    if (m >= M1B){
      int i = m - M1B;
#pragma unroll
      for (int w = 0; w < 2; ++w) us[w] = U1[((size_t)L*16 + i)*2 + w];
      return 1;
    }
    if (m >= M2B){
      int p = m - M2B;
      int i = 0, rem = p; while (rem >= 16-i){ rem -= 16-i; ++i; }
      int j = i + rem;
#pragma unroll
      for (int w = 0; w < 5; ++w){
        float v = U2[(((size_t)L*16 + i)*16 + j)*5 + w];
        if (i < j) v += U2[(((size_t)L*16 + j)*16 + i)*5 + w];
        us[w] = v;
      }
      return 2;
    }
    int p = m >> 4, k = m & 15;
    int i = 0, rem = p; while (rem >= 16-i){ rem -= 16-i; ++i; }
    int j = i + rem;
#pragma unroll
    for (int w = 0; w < 23; ++w){
      float v = U3[((((size_t)L*16 + i)*16 + j)*16 + k)*23 + w];
      if (i < j) v += U3[((((size_t)L*16 + j)*16 + i)*16 + k)*23 + w];
      us[w] = v;
    }
    return 3;
  };

  int cat = gather(m0, us0);
  (void)gather(m0 + 1, us1);

  for (int cc = 0; cc < 16; ++cc){
    float a0 = 0.f, a1 = 0.f;
    if (cat == 3){
#pragma unroll
      for (int w = 0; w < 23; ++w){ float wv = WL[w][cc]; a0 += us0[w]*wv; a1 += us1[w]*wv; }
    } else if (cat == 2){
#pragma unroll
      for (int w = 0; w < 5; ++w){ float wv = WL[23+w][cc]; a0 += us0[w]*wv; a1 += us1[w]*wv; }
    } else if (cat == 1){
#pragma unroll
      for (int w = 0; w < 2; ++w){ float wv = WL[28+w][cc]; a0 += us0[w]*wv; a1 += us1[w]*wv; }
    }
    union { __half2 h; unsigned int u; } hu;
    hu.h = __halves2half2(__float2half(a0), __float2half(a1));
    int cl = cz*16 + cc;
    Bbuf[(((size_t)(e*CN + cl)*NSTEP + s)*64 + l)*4 + r] = hu.u;
  }
}

// ---------------- shared MFMA body, depth-8 register prefetch ----------------
__device__ __forceinline__ void gemm_body(
    const float (&xL)[16], const float (&xH)[16], const uint4* Bp,
    int lane, f32x4& accL, f32x4& accH){
  bool hi_half = (lane & 16) != 0;
  __half2 xselL[4], xselH[4];
#pragma unroll
  for (int q2 = 0; q2 < 4; ++q2){
    int b0 = (hi_half ? 8 : 0) + 2*q2;
    xselL[q2] = __halves2half2(__float2half(xL[b0]), __float2half(xL[b0+1]));
    xselH[q2] = __halves2half2(__float2half(xH[b0]), __float2half(xH[b0+1]));
  }
  bool gsel = (lane & 32) != 0;

  uint4 pb0 = Bp[0*64], pb1 = Bp[1*64], pb2 = Bp[2*64], pb3 = Bp[3*64];
  uint4 pb4 = Bp[4*64], pb5 = Bp[5*64], pb6 = Bp[6*64], pb7 = Bp[7*64];

  sfor<0, NSTEP>([&](auto sc){
    constexpr int s = decltype(sc)::value;
    constexpr int slt = s & 7;
    uint4 cur;
    if constexpr (slt == 0) cur = pb0;
    else if constexpr (slt == 1) cur = pb1;
    else if constexpr (slt == 2) cur = pb2;
    else if constexpr (slt == 3) cur = pb3;
    else if constexpr (slt == 4) cur = pb4;
    else if constexpr (slt == 5) cur = pb5;
    else if constexpr (slt == 6) cur = pb6;
    else cur = pb7;
    if constexpr (s + 8 < NSTEP){
      if constexpr (slt == 0) pb0 = Bp[(size_t)(s+8)*64];
      else if constexpr (slt == 1) pb1 = Bp[(size_t)(s+8)*64];
      else if constexpr (slt == 2) pb2 = Bp[(size_t)(s+8)*64];
      else if constexpr (slt == 3) pb3 = Bp[(size_t)(s+8)*64];
      else if constexpr (slt == 4) pb4 = Bp[(size_t)(s+8)*64];
      else if constexpr (slt == 5) pb5 = Bp[(size_t)(s+8)*64];
      else if constexpr (slt == 6) pb6 = Bp[(size_t)(s+8)*64];
      else pb7 = Bp[(size_t)(s+8)*64];
    }

    f16x8 afL, afH;
    if constexpr (32*(s+1) <= K3DIM){
      constexpr int p0 = 2*s, p1 = 2*s + 1;
      constexpr int iA = pair_i(p0), jA = pair_j(p0);
      constexpr int iB = pair_i(p1), jB = pair_j(p1);
      float pAL = xL[iA]*xL[jA], pBL = xL[iB]*xL[jB];
      float pAH = xH[iA]*xH[jA], pBH = xH[iB]*xH[jB];
      __half2 pvL = __float2half2_rn(gsel ? pBL : pAL);
      __half2 pvH = __float2half2_rn(gsel ? pBH : pAH);
      union { __half2 h[4]; f16x8 v; } uL, uH;
#pragma unroll
      for (int q2 = 0; q2 < 4; ++q2){
        uL.h[q2] = __hmul2(pvL, xselL[q2]);
        uH.h[q2] = __hmul2(pvH, xselH[q2]);
      }
      afL = uL.v; afH = uH.v;
    } else {
      int g = (lane >> 4) & 3;
      if      (g == 0){ afL = tailfrag<s,0>(xL); afH = tailfrag<s,0>(xH); }
      else if (g == 1){ afL = tailfrag<s,1>(xL); afH = tailfrag<s,1>(xH); }
      else if (g == 2){ afL = tailfrag<s,2>(xL); afH = tailfrag<s,2>(xH); }
      else            { afL = tailfrag<s,3>(xL); afH = tailfrag<s,3>(xH); }
    }
    union { uint4 u; f16x8 v; } bc; bc.u = cur;
    accL = __builtin_amdgcn_mfma_f32_16x16x32_f16(afL, bc.v, accL, 0, 0, 0);
    accH = __builtin_amdgcn_mfma_f32_16x16x32_f16(afH, bc.v, accH, 0, 0, 0);
  });
}

// ---------------- main2: compacted wave-task grid, table fused, XCD tiling ----------------
// grid.x = 1088 = 68 slots x 16 c4-groups, block = 256 = 4 waves = 4 c's.
__global__ __launch_bounds__(256) void main2_kernel(
    const float* __restrict__ x, const int* __restrict__ counts,
    const int* __restrict__ bins, const uint4* __restrict__ Bbuf,
    float* __restrict__ out){
  int d = blockIdx.x;
  int q = d >> 3;
  int g16 = (d >> 1) & 3, sh = d & 1;
  int c4 = g16*4 + (q & 3);
  int g  = sh*34 + (q >> 2);

  // fused slot table: derive (e, base) from counts with 4 compares
  int c0 = counts[0], c1 = counts[1], c2 = counts[2], c3 = counts[3];
  int t0 = (c0+31)>>5, t1 = (c1+31)>>5, t2 = (c2+31)>>5, t3 = (c3+31)>>5;
  int ns = t0 + t1 + t2 + t3;
  if (g >= ns) return;
  int e, b0, cnt;
  if (g < t0){ e = 0; b0 = g*32; cnt = c0; }
  else if (g < t0+t1){ e = 1; b0 = (g-t0)*32; cnt = c1; }
  else if (g < t0+t1+t2){ e = 2; b0 = (g-t0-t1)*32; cnt = c2; }
  else { e = 3; b0 = (g-t0-t1-t2)*32; cnt = c3; }

  int wid = threadIdx.x >> 6, lane = threadIdx.x & 63;
  int c = c4*4 + wid;

  int aL = b0 + (lane & 15);
  int aH = aL + 16;
  int nL = (aL < cnt) ? bins[e*NATOMS + aL] : -1;
  int nH = (aH < cnt) ? bins[e*NATOMS + aH] : -1;

  float xL[16], xH[16];
#pragma unroll
  for (int i = 0; i < 16; ++i){
    xL[i] = (nL >= 0) ? x[((size_t)nL*16 + i)*CCH + c] : 0.f;
    xH[i] = (nH >= 0) ? x[((size_t)nH*16 + i)*CCH + c] : 0.f;
  }

  const uint4* Bp = Bbuf + ((size_t)(e*CCH + c))*NSTEP*64 + lane;
  f32x4 accL = {0.f,0.f,0.f,0.f}, accH = {0.f,0.f,0.f,0.f};
  gemm_body(xL, xH, Bp, lane, accL, accH);

  int gp = lane >> 4, L = lane & 15;
#pragma unroll
  for (int r = 0; r < 4; ++r){
    int pl = b0 + 4*gp + r;
    if (pl < cnt){ int n = bins[e*NATOMS + pl]; out[((size_t)n*16 + L)*CCH + c] = accL[r]; }
    int ph = pl + 16;
    if (ph < cnt){ int n = bins[e*NATOMS + ph]; out[((size_t)n*16 + L)*CCH + c] = accH[r]; }
  }
}

// ---------------- legacy main (fallback) ----------------
__global__ __launch_bounds__(256) void main_kernel(
    const float* __restrict__ x, const int* __restrict__ counts,
    const int* __restrict__ bins, const uint4* __restrict__ Bbuf,
    float* __restrict__ out, int CB, int CN){
  int lane = threadIdx.x & 63;
  int wid  = threadIdx.x >> 6;
  int d = blockIdx.x;
  int xcd = d & 7, q = d >> 3;
  int pg = q >> 4, sb = q & 15;
  int p = xcd + 8*pg;
  int e = p / CN, cl = p % CN;
  int slot = sb*4 + wid;
  int cnt = counts[e];
  if (slot * 32 >= cnt) return;
  int c = CB + cl;

  int aL = slot*32 + (lane & 15);
  int aH = aL + 16;
  int nL = (aL < cnt) ? bins[e*NATOMS + aL] : -1;
  int nH = (aH < cnt) ? bins[e*NATOMS + aH] : -1;

  float xL[16], xH[16];
#pragma unroll
  for (int i = 0; i < 16; ++i){
    xL[i] = (nL >= 0) ? x[((size_t)nL*16 + i)*CCH + c] : 0.f;
    xH[i] = (nH >= 0) ? x[((size_t)nH*16 + i)*CCH + c] : 0.f;
  }

  const uint4* Bp = Bbuf + ((size_t)(e*CN + cl))*NSTEP*64 + lane;
  f32x4 accL = {0.f,0.f,0.f,0.f}, accH = {0.f,0.f,0.f,0.f};
  gemm_body(xL, xH, Bp, lane, accL, accH);

  int gp = lane >> 4, L = lane & 15;
#pragma unroll
  for (int r = 0; r < 4; ++r){
    int pl = slot*32 + 4*gp + r;
    if (pl < cnt){ int n = bins[e*NATOMS + pl]; out[((size_t)n*16 + L)*CCH + c] = accL[r]; }
    int ph = pl + 16;
    if (ph < cnt){ int n = bins[e*NATOMS + ph]; out[((size_t)n*16 + L)*CCH + c] = accH[r]; }
  }
}

extern "C" void kernel_launch(void* const* d_in, const int* in_sizes, int n_in,
                              void* d_out, int out_size, void* d_ws, size_t ws_size,
                              hipStream_t stream){
  const float* x   = (const float*)d_in[0];
  const int* types = (const int*)d_in[1];
  const float* U3  = (const float*)d_in[2];
  const float* U2  = (const float*)d_in[3];
  const float* U1  = (const float*)d_in[4];
  const float* W3  = (const float*)d_in[5];
  const float* W2  = (const float*)d_in[6];
  const float* W1  = (const float*)d_in[7];
  float* out = (float*)d_out;

  char* ws = (char*)d_ws;
  int* counts  = (int*)ws;               // +0    (16 B)
  int* bins    = (int*)(ws + 1024);      // +1024 (32 KB) -> ends 33792

  const size_t usOff   = 33792;                               // 512-aligned
  const size_t usBytes = (size_t)KPAD * 16 * 24 * 4;          // 3,588,096
  const size_t bbOff   = usOff + usBytes;                     // 3,621,888 (512-aligned)
  const size_t bbBytes = (size_t)NE * 64 * NSTEP * 64 * 16;   // 19,136,512

  hipMemsetAsync(counts, 0, NE * sizeof(int), stream);
  bin_kernel<<<(NATOMS + 255) / 256, 256, 0, stream>>>(types, counts, bins);

  if (ws_size >= bbOff + bbBytes){
    float* Us = (float*)(ws + usOff);
    unsigned int* Bbuf = (unsigned int*)(ws + bbOff);
    usym_kernel<<<(KPAD*16*6 + 255)/256, 256, 0, stream>>>(U3, U2, U1, Us);
    fold_kernel<<<dim3(NSTEP, NE, 4), 256, 0, stream>>>(Us, W3, W2, W1, Bbuf);
    main2_kernel<<<dim3(MAXSLOTS*16), 256, 0, stream>>>(x, counts, bins, (const uint4*)Bbuf, out);
  } else if (ws_size >= 34816 + bbBytes){
    unsigned int* Bbuf = (unsigned int*)(ws + 34816);
    prep_kernel<<<dim3(NSTEP, NE, 4), 256, 0, stream>>>(U3,U2,U1,W3,W2,W1,Bbuf,0,64);
    main_kernel<<<dim3(NE*64*16), 256, 0, stream>>>(x, counts, bins, (const uint4*)Bbuf, out, 0, 64);
  } else {
    unsigned int* Bbuf = (unsigned int*)(ws + 34816);
    prep_kernel<<<dim3(NSTEP, NE, 2), 256, 0, stream>>>(U3,U2,U1,W3,W2,W1,Bbuf,0,32);
    main_kernel<<<dim3(NE*32*16), 256, 0, stream>>>(x, counts, bins, (const uint4*)Bbuf, out, 0, 32);
    prep_kernel<<<dim3(NSTEP, NE, 2), 256, 0, stream>>>(U3,U2,U1,W3,W2,W1,Bbuf,32,32);
    main_kernel<<<dim3(NE*32*16), 256, 0, stream>>>(x, counts, bins, (const uint4*)Bbuf, out, 32, 32);
  }
}

// Round 7
// 85.433 us; speedup vs baseline: 19.6611x; 1.0512x over previous
//
#include <hip/hip_runtime.h>
#include <hip/hip_fp16.h>

#define NATOMS 2048
#define CCH    64
#define NE     4

#define NP    136     // #{i<=j} pairs over 16
#define K3DIM 2176    // 136*16 inflated order-3 K
#define M2B   2176
#define M1B   2312
#define KTOT  2328
#define KPAD  2336
#define NSTEP 73      // KPAD/32
#define MAXSLOTS 68   // sum ceil(cnt_e/32) <= 64+4

typedef _Float16 f16x8 __attribute__((ext_vector_type(8)));
typedef float f32x4 __attribute__((ext_vector_type(4)));

__host__ __device__ constexpr int pair_i(int p){ int i=0, rem=p; while (rem >= 16-i){ rem -= 16-i; ++i; } return i; }
__host__ __device__ constexpr int pair_j(int p){ int i=0, rem=p; while (rem >= 16-i){ rem -= 16-i; ++i; } return i+rem; }

template<int N> struct IC { static constexpr int value = N; };
template<int S, int E, typename F> __device__ __forceinline__ void sfor(F&& f){
  if constexpr (S < E){ f(IC<S>{}); sfor<S+1,E>(f); }
}

// monomial value for tail region (m >= M2B), compile-time M
template<int M> __device__ __forceinline__ float monval(const float (&xf)[16]){
  if constexpr (M >= KTOT) { (void)xf; return 0.f; }
  else if constexpr (M >= M1B) return xf[M - M1B];
  else {
    constexpr int p  = M - M2B;
    constexpr int i0 = pair_i(p), j0 = pair_j(p);
    return xf[i0] * xf[j0];
  }
}

template<int S, int G> __device__ __forceinline__ f16x8 tailfrag(const float (&xf)[16]){
  union { __half2 h[4]; f16x8 v; } u;
#define TE(E2) { float lo = monval<32*S+8*G+2*E2>(xf); float hi = monval<32*S+8*G+2*E2+1>(xf); \
                 u.h[E2] = __halves2half2(__float2half(lo), __float2half(hi)); }
  TE(0) TE(1) TE(2) TE(3)
#undef TE
  return u.v;
}

// ---------------- bin + usym merged ----------------
// blocks 0..7: binning (8*256 = 2048 = NATOMS threads)
// blocks 8.. : Us[m][L][24] f32, thread computes float4 chunk w = 4q..4q+3
__global__ __launch_bounds__(256) void binusym_kernel(
    const int* __restrict__ types, int* counts, int* bins,
    const float* __restrict__ U3, const float* __restrict__ U2,
    const float* __restrict__ U1, float* __restrict__ Us){
  int b = blockIdx.x;
  if (b < 8){
    int n = b * 256 + threadIdx.x;
    if (n < NATOMS){
      int t = types[n];
      int pos = atomicAdd(&counts[t], 1);
      bins[t * NATOMS + pos] = n;
    }
    return;
  }
  int gid = (b - 8) * 256 + threadIdx.x;
  if (gid >= KPAD * 16 * 6) return;
  int q = gid % 6;
  int t2 = gid / 6;
  int L = t2 & 15, m = t2 >> 4;
  int w0 = q * 4;

  float v[4] = {0.f, 0.f, 0.f, 0.f};
  if (m < M2B){
    int p = m >> 4, k = m & 15;
    int i = 0, rem = p; while (rem >= 16 - i){ rem -= 16 - i; ++i; }
    int j = i + rem;
    const float* r0 = &U3[((((size_t)L*16 + i)*16 + j)*16 + k)*23];
    if (i < j){
      const float* r1 = &U3[((((size_t)L*16 + j)*16 + i)*16 + k)*23];
#pragma unroll
      for (int t = 0; t < 4; ++t){ int w = w0 + t; if (w < 23) v[t] = r0[w] + r1[w]; }
    } else {
#pragma unroll
      for (int t = 0; t < 4; ++t){ int w = w0 + t; if (w < 23) v[t] = r0[w]; }
    }
  } else if (m < M1B){
    if (w0 < 5){
      int p = m - M2B;
      int i = 0, rem = p; while (rem >= 16 - i){ rem -= 16 - i; ++i; }
      int j = i + rem;
#pragma unroll
      for (int t = 0; t < 4; ++t){
        int w = w0 + t;
        if (w < 5){
          float s = U2[(((size_t)L*16 + i)*16 + j)*5 + w];
          if (i < j) s += U2[(((size_t)L*16 + j)*16 + i)*5 + w];
          v[t] = s;
        }
      }
    }
  } else if (m < KTOT){
    if (w0 == 0){
      int i = m - M1B;
      v[0] = U1[((size_t)L*16 + i)*2 + 0];
      v[1] = U1[((size_t)L*16 + i)*2 + 1];
    }
  }
  float4* dst = (float4*)(Us + ((size_t)m*16 + L)*24 + w0);
  *dst = make_float4(v[0], v[1], v[2], v[3]);
}

// ---------------- fold: Bbuf[e][c][s][l][r] = half2{A(m0),A(m0+1)} ----------------
// grid (NSTEP, NE, 4): z splits the 64 channels into 4 groups of 16.
__global__ __launch_bounds__(256) void fold_kernel(
    const float* __restrict__ Us, const float* __restrict__ W3,
    const float* __restrict__ W2, const float* __restrict__ W1,
    unsigned int* __restrict__ Bbuf){
  int s = blockIdx.x, e = blockIdx.y;
  int ccBase = blockIdx.z * 16;
  int tid = threadIdx.x;
  int l = tid >> 2, r = tid & 3, g = l >> 4, L = l & 15;
  int m0 = 32*s + 8*g + 2*r;

  __shared__ float WL[33][16];
  for (int t = tid; t < 33*16; t += 256){
    int row = t >> 4, cc = t & 15;
    int c = ccBase + cc;
    float v = 0.f;
    if (row < 23)      v = W3[((size_t)e*23 + row)*CCH + c];
    else if (row < 28) v = W2[((size_t)e*5 + (row-23))*CCH + c];
    else if (row < 30) v = W1[((size_t)e*2 + (row-28))*CCH + c];
    WL[row][cc] = v;
  }
  __syncthreads();

  const float4* s0 = (const float4*)(Us + ((size_t)m0*16 + L)*24);
  const float4* s1 = (const float4*)(Us + ((size_t)(m0+1)*16 + L)*24);

  const size_t ostride = (size_t)NSTEP*64*4;
  size_t obase = (((size_t)(e*CCH + ccBase)*NSTEP + s)*64 + l)*4 + r;

  if (s < 68){
    float u0[24], u1[24];
#pragma unroll
    for (int q = 0; q < 6; ++q){ ((float4*)u0)[q] = s0[q]; ((float4*)u1)[q] = s1[q]; }
#pragma unroll 4
    for (int cc = 0; cc < 16; ++cc){
      float a0 = 0.f, a1 = 0.f;
#pragma unroll
      for (int w = 0; w < 23; ++w){
        float wv = WL[w][cc];
        a0 += u0[w]*wv; a1 += u1[w]*wv;
      }
      union { __half2 h; unsigned int u; } hu;
      hu.h = __halves2half2(__float2half(a0), __float2half(a1));
      Bbuf[obase + (size_t)cc*ostride] = hu.u;
    }
  } else {
    float u0[8], u1[8];
    ((float4*)u0)[0] = s0[0]; ((float4*)u0)[1] = s0[1];
    ((float4*)u1)[0] = s1[0]; ((float4*)u1)[1] = s1[1];
    int wbase = (m0 < M1B) ? 23 : 28;
#pragma unroll 4
    for (int cc = 0; cc < 16; ++cc){
      float a0 = 0.f, a1 = 0.f;
#pragma unroll
      for (int w = 0; w < 5; ++w){
        float wv = WL[wbase + w][cc];
        a0 += u0[w]*wv; a1 += u1[w]*wv;
      }
      union { __half2 h; unsigned int u; } hu;
      hu.h = __halves2half2(__float2half(a0), __float2half(a1));
      Bbuf[obase + (size_t)cc*ostride] = hu.u;
    }
  }
}

// ---------------- legacy prep (fallback when ws too small) ----------------
__global__ __launch_bounds__(256) void prep_kernel(
    const float* __restrict__ U3, const float* __restrict__ U2,
    const float* __restrict__ U1, const float* __restrict__ W3,
    const float* __restrict__ W2, const float* __restrict__ W1,
    unsigned int* __restrict__ Bbuf, int CB, int CN){
  int s = blockIdx.x, e = blockIdx.y, cz = blockIdx.z;
  int tid = threadIdx.x;
  int l = tid >> 2, r = tid & 3;
  int g = l >> 4, L = l & 15;
  int m0 = 32*s + 8*g + 2*r;

  __shared__ float WL[30][16];
  {
    int cbase = CB + cz*16;
    for (int t = tid; t < 30*16; t += 256){
      int row = t >> 4, cc = t & 15;
      float v;
      if (row < 23)      v = W3[((size_t)e*23 + row)*CCH + cbase + cc];
      else if (row < 28) v = W2[((size_t)e*5 + (row-23))*CCH + cbase + cc];
      else               v = W1[((size_t)e*2 + (row-28))*CCH + cbase + cc];
      WL[row][cc] = v;
    }
  }
  __syncthreads();

  float us0[23], us1[23];
#pragma unroll
  for (int w = 0; w < 23; ++w){ us0[w] = 0.f; us1[w] = 0.f; }

  auto gather = [&](int m, float (&us)[23]) -> int {
    if (m >= KTOT) return 0;
    if (m >= M1B){
      int i = m - M1B;
#pragma unroll
      for (int w = 0; w < 2; ++w) us[w] = U1[((size_t)L*16 + i)*2 + w];
      return 1;
    }
    if (m >= M2B){
      int p = m - M2B;
      int i = 0, rem = p; while (rem >= 16-i){ rem -= 16-i; ++i; }
      int j = i + rem;
#pragma unroll
      for (int w = 0; w < 5; ++w){
        float v = U2[(((size_t)L*16 + i)*16 + j)*5 + w];
        if (i < j) v += U2[(((size_t)L*16 + j)*16 + i)*5 + w];
        us[w] = v;
      }
      return 2;
    }
    int p = m >> 4, k = m & 15;
    int i = 0, rem = p; while (rem >= 16-i){ rem -= 16-i; ++i; }
    int j = i + rem;
#pragma unroll
    for (int w = 0; w < 23; ++w){
      float v = U3[((((size_t)L*16 + i)*16 + j)*16 + k)*23 + w];
      if (i < j) v += U3[((((size_t)L*16 + j)*16 + i)*16 + k)*23 + w];
      us[w] = v;
    }
    return 3;
  };

  int cat = gather(m0, us0);
  (void)gather(m0 + 1, us1);

  for (int cc = 0; cc < 16; ++cc){
    float a0 = 0.f, a1 = 0.f;
    if (cat == 3){
#pragma unroll
      for (int w = 0; w < 23; ++w){ float wv = WL[w][cc]; a0 += us0[w]*wv; a1 += us1[w]*wv; }
    } else if (cat == 2){
#pragma unroll
      for (int w = 0; w < 5; ++w){ float wv = WL[23+w][cc]; a0 += us0[w]*wv; a1 += us1[w]*wv; }
    } else if (cat == 1){
#pragma unroll
      for (int w = 0; w < 2; ++w){ float wv = WL[28+w][cc]; a0 += us0[w]*wv; a1 += us1[w]*wv; }
    }
    union { __half2 h; unsigned int u; } hu;
    hu.h = __halves2half2(__float2half(a0), __float2half(a1));
    int cl = cz*16 + cc;
    Bbuf[(((size_t)(e*CN + cl)*NSTEP + s)*64 + l)*4 + r] = hu.u;
  }
}

// ---------------- shared MFMA body, depth-8 register prefetch ----------------
__device__ __forceinline__ void gemm_body(
    const float (&xL)[16], const float (&xH)[16], const uint4* Bp,
    int lane, f32x4& accL, f32x4& accH){
  bool hi_half = (lane & 16) != 0;
  __half2 xselL[4], xselH[4];
#pragma unroll
  for (int q2 = 0; q2 < 4; ++q2){
    int b0 = (hi_half ? 8 : 0) + 2*q2;
    xselL[q2] = __halves2half2(__float2half(xL[b0]), __float2half(xL[b0+1]));
    xselH[q2] = __halves2half2(__float2half(xH[b0]), __float2half(xH[b0+1]));
  }
  bool gsel = (lane & 32) != 0;

  uint4 pb0 = Bp[0*64], pb1 = Bp[1*64], pb2 = Bp[2*64], pb3 = Bp[3*64];
  uint4 pb4 = Bp[4*64], pb5 = Bp[5*64], pb6 = Bp[6*64], pb7 = Bp[7*64];

  sfor<0, NSTEP>([&](auto sc){
    constexpr int s = decltype(sc)::value;
    constexpr int slt = s & 7;
    uint4 cur;
    if constexpr (slt == 0) cur = pb0;
    else if constexpr (slt == 1) cur = pb1;
    else if constexpr (slt == 2) cur = pb2;
    else if constexpr (slt == 3) cur = pb3;
    else if constexpr (slt == 4) cur = pb4;
    else if constexpr (slt == 5) cur = pb5;
    else if constexpr (slt == 6) cur = pb6;
    else cur = pb7;
    if constexpr (s + 8 < NSTEP){
      if constexpr (slt == 0) pb0 = Bp[(size_t)(s+8)*64];
      else if constexpr (slt == 1) pb1 = Bp[(size_t)(s+8)*64];
      else if constexpr (slt == 2) pb2 = Bp[(size_t)(s+8)*64];
      else if constexpr (slt == 3) pb3 = Bp[(size_t)(s+8)*64];
      else if constexpr (slt == 4) pb4 = Bp[(size_t)(s+8)*64];
      else if constexpr (slt == 5) pb5 = Bp[(size_t)(s+8)*64];
      else if constexpr (slt == 6) pb6 = Bp[(size_t)(s+8)*64];
      else pb7 = Bp[(size_t)(s+8)*64];
    }

    f16x8 afL, afH;
    if constexpr (32*(s+1) <= K3DIM){
      constexpr int p0 = 2*s, p1 = 2*s + 1;
      constexpr int iA = pair_i(p0), jA = pair_j(p0);
      constexpr int iB = pair_i(p1), jB = pair_j(p1);
      float pAL = xL[iA]*xL[jA], pBL = xL[iB]*xL[jB];
      float pAH = xH[iA]*xH[jA], pBH = xH[iB]*xH[jB];
      __half2 pvL = __float2half2_rn(gsel ? pBL : pAL);
      __half2 pvH = __float2half2_rn(gsel ? pBH : pAH);
      union { __half2 h[4]; f16x8 v; } uL, uH;
#pragma unroll
      for (int q2 = 0; q2 < 4; ++q2){
        uL.h[q2] = __hmul2(pvL, xselL[q2]);
        uH.h[q2] = __hmul2(pvH, xselH[q2]);
      }
      afL = uL.v; afH = uH.v;
    } else {
      int g = (lane >> 4) & 3;
      if      (g == 0){ afL = tailfrag<s,0>(xL); afH = tailfrag<s,0>(xH); }
      else if (g == 1){ afL = tailfrag<s,1>(xL); afH = tailfrag<s,1>(xH); }
      else if (g == 2){ afL = tailfrag<s,2>(xL); afH = tailfrag<s,2>(xH); }
      else            { afL = tailfrag<s,3>(xL); afH = tailfrag<s,3>(xH); }
    }
    union { uint4 u; f16x8 v; } bc; bc.u = cur;
    accL = __builtin_amdgcn_mfma_f32_16x16x32_f16(afL, bc.v, accL, 0, 0, 0);
    accH = __builtin_amdgcn_mfma_f32_16x16x32_f16(afH, bc.v, accH, 0, 0, 0);
  });
}

// ---------------- main2: compacted wave-task grid, table fused, XCD tiling ----------------
// grid.x = 1088 = 68 slots x 16 c4-groups, block = 256 = 4 waves = 4 c's.
// __launch_bounds__(256, 4): VGPR cap 128 (>= ~95 live) -> no scratch spill,
// 4 waves/SIMD = 4 blocks/CU -> 1088 blocks ~fully resident.
__global__ __launch_bounds__(256, 4) void main2_kernel(
    const float* __restrict__ x, const int* __restrict__ counts,
    const int* __restrict__ bins, const uint4* __restrict__ Bbuf,
    float* __restrict__ out){
  int d = blockIdx.x;
  int q = d >> 3;
  int g16 = (d >> 1) & 3, sh = d & 1;
  int c4 = g16*4 + (q & 3);
  int g  = sh*34 + (q >> 2);

  // fused slot table: derive (e, base) from counts with 4 compares
  int c0 = counts[0], c1 = counts[1], c2 = counts[2], c3 = counts[3];
  int t0 = (c0+31)>>5, t1 = (c1+31)>>5, t2 = (c2+31)>>5, t3 = (c3+31)>>5;
  int ns = t0 + t1 + t2 + t3;
  if (g >= ns) return;
  int e, b0, cnt;
  if (g < t0){ e = 0; b0 = g*32; cnt = c0; }
  else if (g < t0+t1){ e = 1; b0 = (g-t0)*32; cnt = c1; }
  else if (g < t0+t1+t2){ e = 2; b0 = (g-t0-t1)*32; cnt = c2; }
  else { e = 3; b0 = (g-t0-t1-t2)*32; cnt = c3; }

  int wid = threadIdx.x >> 6, lane = threadIdx.x & 63;
  int c = c4*4 + wid;

  int aL = b0 + (lane & 15);
  int aH = aL + 16;
  int nL = (aL < cnt) ? bins[e*NATOMS + aL] : -1;
  int nH = (aH < cnt) ? bins[e*NATOMS + aH] : -1;

  float xL[16], xH[16];
#pragma unroll
  for (int i = 0; i < 16; ++i){
    xL[i] = (nL >= 0) ? x[((size_t)nL*16 + i)*CCH + c] : 0.f;
    xH[i] = (nH >= 0) ? x[((size_t)nH*16 + i)*CCH + c] : 0.f;
  }

  const uint4* Bp = Bbuf + ((size_t)(e*CCH + c))*NSTEP*64 + lane;
  f32x4 accL = {0.f,0.f,0.f,0.f}, accH = {0.f,0.f,0.f,0.f};
  gemm_body(xL, xH, Bp, lane, accL, accH);

  int gp = lane >> 4, L = lane & 15;
#pragma unroll
  for (int r = 0; r < 4; ++r){
    int pl = b0 + 4*gp + r;
    if (pl < cnt){ int n = bins[e*NATOMS + pl]; out[((size_t)n*16 + L)*CCH + c] = accL[r]; }
    int ph = pl + 16;
    if (ph < cnt){ int n = bins[e*NATOMS + ph]; out[((size_t)n*16 + L)*CCH + c] = accH[r]; }
  }
}

// ---------------- legacy main (fallback) ----------------
__global__ __launch_bounds__(256, 4) void main_kernel(
    const float* __restrict__ x, const int* __restrict__ counts,
    const int* __restrict__ bins, const uint4* __restrict__ Bbuf,
    float* __restrict__ out, int CB, int CN){
  int lane = threadIdx.x & 63;
  int wid  = threadIdx.x >> 6;
  int d = blockIdx.x;
  int xcd = d & 7, q = d >> 3;
  int pg = q >> 4, sb = q & 15;
  int p = xcd + 8*pg;
  int e = p / CN, cl = p % CN;
  int slot = sb*4 + wid;
  int cnt = counts[e];
  if (slot * 32 >= cnt) return;
  int c = CB + cl;

  int aL = slot*32 + (lane & 15);
  int aH = aL + 16;
  int nL = (aL < cnt) ? bins[e*NATOMS + aL] : -1;
  int nH = (aH < cnt) ? bins[e*NATOMS + aH] : -1;

  float xL[16], xH[16];
#pragma unroll
  for (int i = 0; i < 16; ++i){
    xL[i] = (nL >= 0) ? x[((size_t)nL*16 + i)*CCH + c] : 0.f;
    xH[i] = (nH >= 0) ? x[((size_t)nH*16 + i)*CCH + c] : 0.f;
  }

  const uint4* Bp = Bbuf + ((size_t)(e*CN + cl))*NSTEP*64 + lane;
  f32x4 accL = {0.f,0.f,0.f,0.f}, accH = {0.f,0.f,0.f,0.f};
  gemm_body(xL, xH, Bp, lane, accL, accH);

  int gp = lane >> 4, L = lane & 15;
#pragma unroll
  for (int r = 0; r < 4; ++r){
    int pl = slot*32 + 4*gp + r;
    if (pl < cnt){ int n = bins[e*NATOMS + pl]; out[((size_t)n*16 + L)*CCH + c] = accL[r]; }
    int ph = pl + 16;
    if (ph < cnt){ int n = bins[e*NATOMS + ph]; out[((size_t)n*16 + L)*CCH + c] = accH[r]; }
  }
}

extern "C" void kernel_launch(void* const* d_in, const int* in_sizes, int n_in,
                              void* d_out, int out_size, void* d_ws, size_t ws_size,
                              hipStream_t stream){
  const float* x   = (const float*)d_in[0];
  const int* types = (const int*)d_in[1];
  const float* U3  = (const float*)d_in[2];
  const float* U2  = (const float*)d_in[3];
  const float* U1  = (const float*)d_in[4];
  const float* W3  = (const float*)d_in[5];
  const float* W2  = (const float*)d_in[6];
  const float* W1  = (const float*)d_in[7];
  float* out = (float*)d_out;

  char* ws = (char*)d_ws;
  int* counts  = (int*)ws;               // +0    (16 B)
  int* bins    = (int*)(ws + 1024);      // +1024 (32 KB) -> ends 33792

  const size_t usOff   = 33792;                               // 512-aligned
  const size_t usBytes = (size_t)KPAD * 16 * 24 * 4;          // 3,588,096
  const size_t bbOff   = usOff + usBytes;                     // 3,621,888 (512-aligned)
  const size_t bbBytes = (size_t)NE * 64 * NSTEP * 64 * 16;   // 19,136,512

  hipMemsetAsync(counts, 0, NE * sizeof(int), stream);

  if (ws_size >= bbOff + bbBytes){
    float* Us = (float*)(ws + usOff);
    unsigned int* Bbuf = (unsigned int*)(ws + bbOff);
    int usymBlocks = (KPAD*16*6 + 255)/256;
    binusym_kernel<<<8 + usymBlocks, 256, 0, stream>>>(types, counts, bins, U3, U2, U1, Us);
    fold_kernel<<<dim3(NSTEP, NE, 4), 256, 0, stream>>>(Us, W3, W2, W1, Bbuf);
    main2_kernel<<<dim3(MAXSLOTS*16), 256, 0, stream>>>(x, counts, bins, (const uint4*)Bbuf, out);
  } else if (ws_size >= 34816 + bbBytes){
    unsigned int* Bbuf = (unsigned int*)(ws + 34816);
    binusym_kernel<<<8, 256, 0, stream>>>(types, counts, bins, U3, U2, U1, (float*)(ws + usOff));
    prep_kernel<<<dim3(NSTEP, NE, 4), 256, 0, stream>>>(U3,U2,U1,W3,W2,W1,Bbuf,0,64);
    main_kernel<<<dim3(NE*64*16), 256, 0, stream>>>(x, counts, bins, (const uint4*)Bbuf, out, 0, 64);
  } else {
    unsigned int* Bbuf = (unsigned int*)(ws + 34816);
    binusym_kernel<<<8, 256, 0, stream>>>(types, counts, bins, U3, U2, U1, (float*)(ws + usOff));
    prep_kernel<<<dim3(NSTEP, NE, 2), 256, 0, stream>>>(U3,U2,U1,W3,W2,W1,Bbuf,0,32);
    main_kernel<<<dim3(NE*32*16), 256, 0, stream>>>(x, counts, bins, (const uint4*)Bbuf, out, 0, 32);
    prep_kernel<<<dim3(NSTEP, NE, 2), 256, 0, stream>>>(U3,U2,U1,W3,W2,W1,Bbuf,32,32);
    main_kernel<<<dim3(NE*32*16), 256, 0, stream>>>(x, counts, bins, (const uint4*)Bbuf, out, 32, 32);
  }
}